// Round 14
// baseline (88.146 us; speedup 1.0000x reference)
//
#include <hip/hip_runtime.h>
#include <hip/hip_bf16.h>
#include <stdint.h>

#define NBATCH 16
#define NT 2048
#define NC 64
#define QT 128
#define KT 128
#define SC_LOG2E 11.5415603f  // 8 * log2(e)

typedef __bf16 bf16x8 __attribute__((ext_vector_type(8)));
typedef float f32x4 __attribute__((ext_vector_type(4)));
typedef float f32x16 __attribute__((ext_vector_type(16)));

#define Z16 {0.f,0.f,0.f,0.f,0.f,0.f,0.f,0.f,0.f,0.f,0.f,0.f,0.f,0.f,0.f,0.f}

extern "C" __device__ float __ocml_exp2_f32(float);

static __device__ __forceinline__ unsigned short f2bf(float f) {
  __bf16 h = (__bf16)f;  // hardware RTNE convert
  union { __bf16 h; unsigned short u; } a; a.h = h; return a.u;
}
static __device__ __forceinline__ float bf2f(unsigned short h) {
  union { uint32_t u; float f; } a; a.u = ((uint32_t)h) << 16;
  return a.f;
}
static __device__ __forceinline__ float fasu(uint32_t u) {
  union { uint32_t u; float f; } a; a.u = u; return a.f;
}
static __device__ __forceinline__ uint32_t uasf(float f) {
  union { float f; uint32_t u; } a; a.f = f; return a.u;
}

#define GLD_LDS16(gsrc, ldst)                                                  \
  __builtin_amdgcn_global_load_lds(                                            \
      (const __attribute__((address_space(1))) void*)(gsrc),                   \
      (__attribute__((address_space(3))) void*)(ldst), 16, 0, 0)

// ---------------------------------------------------------------------------
// Kernel 0: one-time W transpose + hi/lo bf16 split. 3 blocks (k,q,v).
// ---------------------------------------------------------------------------
__global__ __launch_bounds__(256, 2) void prep_w(
    const float* __restrict__ Wk, const float* __restrict__ Wq,
    const float* __restrict__ Wv,
    unsigned short* __restrict__ wt_hi, unsigned short* __restrict__ wt_lo)
{
  __shared__ unsigned short hbuf[64][66];
  __shared__ unsigned short lbuf[64][66];
  const int m = (int)blockIdx.x;
  const float* Wm = (m == 0) ? Wk : (m == 1 ? Wq : Wv);
  const int tid = (int)threadIdx.x;
  for (int idx = tid; idx < 1024; idx += 256) {
    int c = idx >> 4, o4 = (idx & 15) * 4;
    float4 v = *(const float4*)(Wm + c * 64 + o4);
    float vals[4] = {v.x, v.y, v.z, v.w};
#pragma unroll
    for (int j = 0; j < 4; ++j) {
      unsigned short h = f2bf(vals[j]);
      hbuf[o4 + j][c] = h;
      lbuf[o4 + j][c] = f2bf(vals[j] - bf2f(h));
    }
  }
  __syncthreads();
  for (int idx = tid; idx < 1024; idx += 256) {
    int o = idx >> 4, c0 = (idx & 15) * 4;
    ushort4 hv, lv;
    hv.x = hbuf[o][c0]; hv.y = hbuf[o][c0 + 1];
    hv.z = hbuf[o][c0 + 2]; hv.w = hbuf[o][c0 + 3];
    lv.x = lbuf[o][c0]; lv.y = lbuf[o][c0 + 1];
    lv.z = lbuf[o][c0 + 2]; lv.w = lbuf[o][c0 + 3];
    *(ushort4*)(wt_hi + (size_t)(m * 64 + o) * 64 + c0) = hv;
    *(ushort4*)(wt_lo + (size_t)(m * 64 + o) * 64 + c0) = lv;
  }
}

// ---------------------------------------------------------------------------
// Kernel 1: q,k,v projections. 64 rows per block. (r13 validated)
// ---------------------------------------------------------------------------
__global__ __launch_bounds__(256, 2) void proj_kernel(
    const float* __restrict__ x,
    const unsigned short* __restrict__ wt_hi, const unsigned short* __restrict__ wt_lo,
    const float* __restrict__ bk, const float* __restrict__ bq, const float* __restrict__ bv,
    unsigned short* __restrict__ khi, unsigned short* __restrict__ klo,
    unsigned short* __restrict__ qhi, unsigned short* __restrict__ qlo,
    unsigned short* __restrict__ vt)
{
  __shared__ __align__(16) char smem[65536];
  const int XH = 0, XL = 8192, WTH = 16384, WTL = 40960, VTB = 0; // VTB aliases XH
  const int tid = (int)threadIdx.x;
  const int l = tid & 63, w = tid >> 6;
  const int lr = l & 15, lg = l >> 4;
  const int blk = (int)blockIdx.x;
  const int rowbase = blk * 64;
  const int bb = blk >> 5;          // 32 blocks per batch

  // issue ALL x loads first (4 float4/thread in flight)
  float4 xv[4];
#pragma unroll
  for (int j = 0; j < 4; ++j) {
    int c = tid + j * 256;
    int row = c >> 4, d0 = (c & 15) * 4;
    xv[j] = *(const float4*)(x + (size_t)(rowbase + row) * NC + d0);
  }
  // stage W^T hi/lo (24 KB each) via global_load_lds, pre-swizzled source
#pragma unroll
  for (int ch4 = 0; ch4 < 6; ++ch4) {
    int ch = ch4 * 4 + w;           // 24 chunks of 1KB per region
    int d = ch * 1024 + l * 16;
    int swk = d ^ (((d >> 7) & 7) << 4);
    GLD_LDS16((const char*)wt_hi + swk, smem + WTH + ch * 1024);
    GLD_LDS16((const char*)wt_lo + swk, smem + WTL + ch * 1024);
  }
  // convert + write x tile (64x64) as hi/lo bf16, swizzled
#pragma unroll
  for (int j = 0; j < 4; ++j) {
    int c = tid + j * 256;
    int row = c >> 4, d0 = (c & 15) * 4;
    unsigned short h0 = f2bf(xv[j].x), h1 = f2bf(xv[j].y), h2 = f2bf(xv[j].z), h3 = f2bf(xv[j].w);
    unsigned short m0 = f2bf(xv[j].x - bf2f(h0)), m1 = f2bf(xv[j].y - bf2f(h1));
    unsigned short m2 = f2bf(xv[j].z - bf2f(h2)), m3 = f2bf(xv[j].w - bf2f(h3));
    uint2 ph, pl;
    ph.x = (uint32_t)h0 | ((uint32_t)h1 << 16); ph.y = (uint32_t)h2 | ((uint32_t)h3 << 16);
    pl.x = (uint32_t)m0 | ((uint32_t)m1 << 16); pl.y = (uint32_t)m2 | ((uint32_t)m3 << 16);
    int byteoff = (row * 128 + d0 * 2) ^ ((row & 7) << 4);
    *(uint2*)(smem + XH + byteoff) = ph;
    *(uint2*)(smem + XL + byteoff) = pl;
  }
  __syncthreads();

  // x B-frags for this wave's 16 rows (t = w*16 + lr)
  bf16x8 xh[2], xl[2];
  {
    int row = w * 16 + lr;
#pragma unroll
    for (int dc = 0; dc < 2; ++dc) {
      int byteoff = (row * 128 + (dc * 32 + lg * 8) * 2) ^ ((row & 7) << 4);
      xh[dc] = *(const bf16x8*)(smem + XH + byteoff);
      xl[dc] = *(const bf16x8*)(smem + XL + byteoff);
    }
  }
  // A = W^T (rows og -> C reg dim), B = x (rows t -> C lane dim)
  f32x4 acc[12];
#pragma unroll
  for (int nb = 0; nb < 12; ++nb) {
    f32x4 a = {0.f, 0.f, 0.f, 0.f};
    int og = nb * 16 + lr;
#pragma unroll
    for (int dc = 0; dc < 2; ++dc) {
      int byteoff = (og * 128 + (dc * 32 + lg * 8) * 2) ^ ((og & 7) << 4);
      bf16x8 bh = *(const bf16x8*)(smem + WTH + byteoff);
      bf16x8 bl = *(const bf16x8*)(smem + WTL + byteoff);
      a = __builtin_amdgcn_mfma_f32_16x16x32_bf16(bh, xh[dc], a, 0, 0, 0);
      a = __builtin_amdgcn_mfma_f32_16x16x32_bf16(bl, xh[dc], a, 0, 0, 0);
      a = __builtin_amdgcn_mfma_f32_16x16x32_bf16(bh, xl[dc], a, 0, 0, 0);
    }
    acc[nb] = a;
  }
  __syncthreads();  // done reading XH/XL; VTB may now alias

  // epilogue: lane holds t = w*16+lr, og = nb*16 + lg*4 + r (4 consecutive)
  const int tloc = w * 16 + lr;
  const size_t gt = (size_t)(rowbase + tloc);
#pragma unroll
  for (int nb = 0; nb < 12; ++nb) {
    int ogb = (nb & 3) * 16 + lg * 4;
    const float* bp = (nb < 4) ? bk : (nb < 8 ? bq : bv);
    float4 bias = *(const float4*)(bp + ogb);
    float v0 = acc[nb][0] + bias.x, v1 = acc[nb][1] + bias.y,
          v2 = acc[nb][2] + bias.z, v3 = acc[nb][3] + bias.w;
    if (nb < 8) {
      if (nb >= 4) { v0 *= SC_LOG2E; v1 *= SC_LOG2E; v2 *= SC_LOG2E; v3 *= SC_LOG2E; }
      ushort4 hv, lv;
      hv.x = f2bf(v0); lv.x = f2bf(v0 - bf2f(hv.x));
      hv.y = f2bf(v1); lv.y = f2bf(v1 - bf2f(hv.y));
      hv.z = f2bf(v2); lv.z = f2bf(v2 - bf2f(hv.z));
      hv.w = f2bf(v3); lv.w = f2bf(v3 - bf2f(hv.w));
      unsigned short* dH = (nb < 4) ? khi : qhi;
      unsigned short* dL = (nb < 4) ? klo : qlo;
      *(ushort4*)(dH + gt * 64 + ogb) = hv;
      *(ushort4*)(dL + gt * 64 + ogb) = lv;
    } else {
      float vs[4] = {v0, v1, v2, v3};
#pragma unroll
      for (int r = 0; r < 4; ++r) {
        int o = ogb + r;
        int byteoff = (o * 128 + tloc * 2) ^ ((o & 7) << 4);
        *(unsigned short*)(smem + VTB + byteoff) = f2bf(vs[r]);
      }
    }
  }
  __syncthreads();
  for (int cc = tid; cc < 512; cc += 256) {
    int o = cc >> 3, t0 = (cc & 7) * 8;
    int byteoff = (o * 128 + t0 * 2) ^ ((o & 7) << 4);
    uint4 v = *(const uint4*)(smem + VTB + byteoff);
    *(uint4*)(vt + ((size_t)bb * 64 + o) * NT + (size_t)(blk & 31) * 64 + t0) = v;
  }
}

// ---------------------------------------------------------------------------
// Kernel 2: flash attention — r13 structure with (a) __launch_bounds__(1024,1)
// (the old "4" forced a 64-VGPR cap; LDS already limits to 1 block/CU so this
// costs no occupancy and doubles the register budget) and (b) the round-7
// validated 3-independent-chain QK^T (breaks the 12-deep MFMA dep chain).
// ---------------------------------------------------------------------------
__global__ __launch_bounds__(1024, 1) void attn_kernel(
    const unsigned short* __restrict__ khi, const unsigned short* __restrict__ klo,
    const unsigned short* __restrict__ qhi, const unsigned short* __restrict__ qlo,
    const unsigned short* __restrict__ vt,
    float* __restrict__ out)
{
  __shared__ __align__(16) char smem[98304];
  const int BUF = 49152;   // per-buffer: KHI 16K | KLO 16K | VT 16K
  const int MLB = 65536;   // epilogue m/l exchange (aliases buf space)
  const int tid = (int)threadIdx.x;
  const int l = tid & 63, w = tid >> 6;     // w in 0..15
  const int lq = l & 31;
  const bool hi = (l >= 32);
  const int hioff = hi ? 16 : 0;
  const int r = w & 3;                      // q-group: rows 32r..32r+31
  const int cc = w >> 2;                    // key quarter: keys 32cc..32cc+31
  const int lb = ((int)(blockIdx.x & 7) << 5) | ((int)blockIdx.x >> 3);
  const int bb = lb >> 4;
  const int qt = lb & 15;

  const char* kh_base = (const char*)(khi + (size_t)bb * NT * 64);
  const char* kl_base = (const char*)(klo + (size_t)bb * NT * 64);
  const char* v_base  = (const char*)(vt + (size_t)bb * 64 * NT);

#define STAGE_TILE(bufp_, it_)                                                 \
  do {                                                                         \
    const char* kh_t = kh_base + (size_t)(it_) * 16384;                        \
    const char* kl_t = kl_base + (size_t)(it_) * 16384;                        \
    const char* v_tb = v_base + (size_t)(it_) * 256;                           \
    int d_ = w * 1024 + l * 16;                                                \
    int swk_ = d_ ^ (((d_ >> 7) & 7) << 4);                                    \
    GLD_LDS16(kh_t + swk_, (bufp_) + w * 1024);                                \
    GLD_LDS16(kl_t + swk_, (bufp_) + 16384 + w * 1024);                        \
    int o_ = d_ >> 8;                                                          \
    int swv_ = (d_ & 255) ^ ((o_ & 7) << 4);                                   \
    GLD_LDS16(v_tb + (size_t)o_ * 4096 + swv_, (bufp_) + 32768 + w * 1024);    \
  } while (0)

  // prologue: stage tile 0; load Q fragments (rows 32r..32r+31, B-operand)
  STAGE_TILE(smem, 0);
  bf16x8 Qh[4], Ql[4];
  {
    const char* qh_t = (const char*)qhi + ((size_t)bb * NT + (size_t)qt * QT) * 128;
    const char* ql_t = (const char*)qlo + ((size_t)bb * NT + (size_t)qt * QT) * 128;
    int qrow = r * 32 + lq;
#pragma unroll
    for (int dc = 0; dc < 4; ++dc) {
      Qh[dc] = *(const bf16x8*)(qh_t + qrow * 128 + dc * 32 + hioff);
      Ql[dc] = *(const bf16x8*)(ql_t + qrow * 128 + dc * 32 + hioff);
    }
  }
  asm volatile("s_waitcnt vmcnt(0)" ::: "memory");
  __builtin_amdgcn_s_barrier();
  asm volatile("" ::: "memory");

  f32x16 O0 = Z16, O1 = Z16;
  float mrun = -1e30f, lrun = 0.f;
  const int swr = (lq & 7) << 4;

  for (int it = 0; it < NT / KT; ++it) {
    char* cb = smem + (it & 1) * BUF;
    if (it + 1 < NT / KT) STAGE_TILE(smem + ((it + 1) & 1) * BUF, it + 1);

    // --- S^T[key][q] = K · Q^T: 3 INDEPENDENT chains (depth 4 each, r7-validated)
    f32x16 T1 = Z16, T2 = Z16, T3 = Z16;
    __builtin_amdgcn_s_setprio(1);
    {
      int krow = cc * 32 + lq;
#pragma unroll
      for (int dc = 0; dc < 4; ++dc) {
        int cchunk = (dc * 32 + hioff) ^ swr;
        bf16x8 Ah = *(const bf16x8*)(cb + krow * 128 + cchunk);
        bf16x8 Al = *(const bf16x8*)(cb + 16384 + krow * 128 + cchunk);
        T1 = __builtin_amdgcn_mfma_f32_32x32x16_bf16(Ah, Qh[dc], T1, 0, 0, 0);
        T2 = __builtin_amdgcn_mfma_f32_32x32x16_bf16(Al, Qh[dc], T2, 0, 0, 0);
        T3 = __builtin_amdgcn_mfma_f32_32x32x16_bf16(Ah, Ql[dc], T3, 0, 0, 0);
      }
    }
    __builtin_amdgcn_s_setprio(0);
    f32x16 S = (T1 + T2) + T3;

    // --- online softmax in log2 units; tree + permlane cross-half reduce
    float m01 = fmaxf(S[0], S[1]),   m23 = fmaxf(S[2], S[3]);
    float m45 = fmaxf(S[4], S[5]),   m67 = fmaxf(S[6], S[7]);
    float m89 = fmaxf(S[8], S[9]),   mab = fmaxf(S[10], S[11]);
    float mcd = fmaxf(S[12], S[13]), mef = fmaxf(S[14], S[15]);
    float pmax = fmaxf(fmaxf(fmaxf(m01, m23), fmaxf(m45, m67)),
                       fmaxf(fmaxf(m89, mab), fmaxf(mcd, mef)));
    {
      auto sw = __builtin_amdgcn_permlane32_swap(uasf(pmax), uasf(pmax), false, false);
      pmax = fmaxf(fasu(sw[0]), fasu(sw[1]));
    }
    if (__any(pmax > mrun + 11.55f)) {      // defer-max (e^1 logit window)
      float mnew = fmaxf(mrun, pmax);
      float alpha = __ocml_exp2_f32(mrun - mnew);
      O0 *= alpha; O1 *= alpha; lrun *= alpha; mrun = mnew;
    }
    float p[16];
#pragma unroll
    for (int i = 0; i < 16; ++i) p[i] = __ocml_exp2_f32(S[i] - mrun);
    float s01 = p[0] + p[1],   s23 = p[2] + p[3];
    float s45 = p[4] + p[5],   s67 = p[6] + p[7];
    float s89 = p[8] + p[9],   sab = p[10] + p[11];
    float scd = p[12] + p[13], sef = p[14] + p[15];
    float ts = ((s01 + s23) + (s45 + s67)) + ((s89 + sab) + (scd + sef));
    {
      auto sw = __builtin_amdgcn_permlane32_swap(uasf(ts), uasf(ts), false, false);
      ts = fasu(sw[0]) + fasu(sw[1]);
    }
    lrun += ts;

    // --- O^T += V^T · P^T  (A = V^T frag from LDS, B = P^T in-register)
#define PV_CHUNK(kc_)                                                          \
    {                                                                          \
      const int b_ = 8 * (kc_);                                                \
      uint32_t X0, X1, Y0, Y1;                                                 \
      asm("v_cvt_pk_bf16_f32 %0, %1, %2" : "=v"(X0) : "v"(p[b_+0]), "v"(p[b_+1])); \
      asm("v_cvt_pk_bf16_f32 %0, %1, %2" : "=v"(X1) : "v"(p[b_+2]), "v"(p[b_+3])); \
      asm("v_cvt_pk_bf16_f32 %0, %1, %2" : "=v"(Y0) : "v"(p[b_+4]), "v"(p[b_+5])); \
      asm("v_cvt_pk_bf16_f32 %0, %1, %2" : "=v"(Y1) : "v"(p[b_+6]), "v"(p[b_+7])); \
      auto sw0 = __builtin_amdgcn_permlane32_swap(X0, Y0, false, false);       \
      auto sw1 = __builtin_amdgcn_permlane32_swap(X1, Y1, false, false);       \
      union { uint32_t u[4]; bf16x8 v; } cvb;                                  \
      cvb.u[0] = sw0[0]; cvb.u[1] = sw1[0];                                    \
      cvb.u[2] = sw0[1]; cvb.u[3] = sw1[1];                                    \
      bf16x8 Bp = cvb.v;                                                       \
      int vcol = 64 * cc + 32 * (kc_) + hioff;                                 \
      {                                                                        \
        bf16x8 Av = *(const bf16x8*)(cb + 32768 + lq * 256 + (vcol ^ swr));    \
        O0 = __builtin_amdgcn_mfma_f32_32x32x16_bf16(Av, Bp, O0, 0, 0, 0);     \
      }                                                                        \
      {                                                                        \
        bf16x8 Av = *(const bf16x8*)(cb + 32768 + (32 + lq) * 256 + (vcol ^ swr)); \
        O1 = __builtin_amdgcn_mfma_f32_32x32x16_bf16(Av, Bp, O1, 0, 0, 0);     \
      }                                                                        \
    }
    __builtin_amdgcn_s_setprio(1);
    PV_CHUNK(0)
    PV_CHUNK(1)
    __builtin_amdgcn_s_setprio(0);
#undef PV_CHUNK

    // tail: drain next tile's loads (flew during compute), then publish
    asm volatile("s_waitcnt vmcnt(0)" ::: "memory");
    __builtin_amdgcn_s_barrier();
    asm volatile("" ::: "memory");
    __builtin_amdgcn_sched_barrier(0);
  }

  // --- epilogue: 2-stage 4-way split-K merge, then direct f32x4 stores
  const int lsw = (l & 7) << 4;
#define DUMP(idx_)                                                             \
  {                                                                            \
    char* dd = smem + (idx_) * 8192 + l * 128;                                 \
    _Pragma("unroll")                                                          \
    for (int g = 0; g < 4; ++g) {                                              \
      f32x4 t0, t1;                                                            \
      _Pragma("unroll")                                                        \
      for (int j = 0; j < 4; ++j) { t0[j] = O0[4*g+j]; t1[j] = O1[4*g+j]; }    \
      *(f32x4*)(dd + ((g * 16) ^ lsw)) = t0;                                   \
      *(f32x4*)(dd + ((64 + g * 16) ^ lsw)) = t1;                              \
    }                                                                          \
    *(float*)(smem + MLB + (idx_) * 256 + lq * 8) = mrun;                      \
    *(float*)(smem + MLB + (idx_) * 256 + lq * 8 + 4) = lrun;                  \
  }
#define MERGE(idx_)                                                            \
  {                                                                            \
    const char* ds = smem + (idx_) * 8192 + l * 128;                           \
    float m1 = *(const float*)(smem + MLB + (idx_) * 256 + lq * 8);            \
    float l1 = *(const float*)(smem + MLB + (idx_) * 256 + lq * 8 + 4);        \
    float M = fmaxf(mrun, m1);                                                 \
    float a0 = __ocml_exp2_f32(mrun - M);                                      \
    float a1 = __ocml_exp2_f32(m1 - M);                                        \
    lrun = lrun * a0 + l1 * a1;                                                \
    mrun = M;                                                                  \
    _Pragma("unroll")                                                          \
    for (int g = 0; g < 4; ++g) {                                              \
      f32x4 o1a = *(const f32x4*)(ds + ((g * 16) ^ lsw));                      \
      f32x4 o1b = *(const f32x4*)(ds + ((64 + g * 16) ^ lsw));                 \
      _Pragma("unroll")                                                        \
      for (int j = 0; j < 4; ++j) {                                            \
        O0[4*g+j] = O0[4*g+j] * a0 + o1a[j] * a1;                              \
        O1[4*g+j] = O1[4*g+j] * a0 + o1b[j] * a1;                              \
      }                                                                        \
    }                                                                          \
  }
  if (cc & 1) DUMP(r * 2 + (cc >> 1));      // cc=1 -> idx 2r, cc=3 -> idx 2r+1
  __syncthreads();
  if (!(cc & 1)) MERGE(r * 2 + (cc >> 1));  // cc=0 takes cc=1, cc=2 takes cc=3
  __syncthreads();
  if (cc == 2) DUMP(r * 2 + 1);
  __syncthreads();
  if (cc == 0) {
    MERGE(r * 2 + 1);
    float inv = 1.0f / lrun;
    float* orow = out + ((size_t)bb * NT + (size_t)qt * QT + r * 32 + lq) * 64;
#pragma unroll
    for (int g = 0; g < 4; ++g) {
      int d0 = 8 * g + (hi ? 4 : 0);
      f32x4 s0, s1;
#pragma unroll
      for (int j = 0; j < 4; ++j) { s0[j] = O0[4*g+j] * inv; s1[j] = O1[4*g+j] * inv; }
      *(f32x4*)(orow + d0) = s0;
      *(f32x4*)(orow + d0 + 32) = s1;
    }
  }
#undef DUMP
#undef MERGE
#undef STAGE_TILE
}

extern "C" void kernel_launch(void* const* d_in, const int* in_sizes, int n_in,
                              void* d_out, int out_size, void* d_ws, size_t ws_size,
                              hipStream_t stream) {
  const float* x  = (const float*)d_in[0];
  const float* Wk = (const float*)d_in[1];
  const float* bk = (const float*)d_in[2];
  const float* Wq = (const float*)d_in[3];
  const float* bq = (const float*)d_in[4];
  const float* Wv = (const float*)d_in[5];
  const float* bv = (const float*)d_in[6];
  float* out = (float*)d_out;

  const size_t NE = (size_t)NBATCH * NT * 64;
  unsigned short* ws = (unsigned short*)d_ws;
  unsigned short* khi = ws;
  unsigned short* klo = ws + NE;
  unsigned short* qhi = ws + 2 * NE;
  unsigned short* qlo = ws + 3 * NE;
  unsigned short* vt  = ws + 4 * NE;
  unsigned short* wt_hi = ws + 5 * NE;
  unsigned short* wt_lo = wt_hi + 192 * 64;

  prep_w<<<dim3(3), dim3(256), 0, stream>>>(Wk, Wq, Wv, wt_hi, wt_lo);
  proj_kernel<<<dim3((NBATCH * NT) / 64), dim3(256), 0, stream>>>(
      x, wt_hi, wt_lo, bk, bq, bv, khi, klo, qhi, qlo, vt);
  attn_kernel<<<dim3(NBATCH * (NT / QT)), dim3(1024), 0, stream>>>(
      khi, klo, qhi, qlo, vt, out);
}

// Round 15
// 74.755 us; speedup vs baseline: 1.1791x; 1.1791x over previous
//
#include <hip/hip_runtime.h>
#include <hip/hip_bf16.h>
#include <stdint.h>

#define NBATCH 16
#define NT 2048
#define NC 64
#define QT 128
#define KT 128
#define SC_LOG2E 11.5415603f  // 8 * log2(e)

typedef __bf16 bf16x8 __attribute__((ext_vector_type(8)));
typedef float f32x4 __attribute__((ext_vector_type(4)));
typedef float f32x16 __attribute__((ext_vector_type(16)));

#define Z16 {0.f,0.f,0.f,0.f,0.f,0.f,0.f,0.f,0.f,0.f,0.f,0.f,0.f,0.f,0.f,0.f}

extern "C" __device__ float __ocml_exp2_f32(float);

static __device__ __forceinline__ unsigned short f2bf(float f) {
  __bf16 h = (__bf16)f;  // hardware RTNE convert
  union { __bf16 h; unsigned short u; } a; a.h = h; return a.u;
}
static __device__ __forceinline__ float bf2f(unsigned short h) {
  union { uint32_t u; float f; } a; a.u = ((uint32_t)h) << 16;
  return a.f;
}
static __device__ __forceinline__ float fasu(uint32_t u) {
  union { uint32_t u; float f; } a; a.u = u; return a.f;
}
static __device__ __forceinline__ uint32_t uasf(float f) {
  union { float f; uint32_t u; } a; a.f = f; return a.u;
}

#define GLD_LDS16(gsrc, ldst)                                                  \
  __builtin_amdgcn_global_load_lds(                                            \
      (const __attribute__((address_space(1))) void*)(gsrc),                   \
      (__attribute__((address_space(3))) void*)(ldst), 16, 0, 0)

// ---------------------------------------------------------------------------
// Kernel 0: one-time W transpose + hi/lo bf16 split. 3 blocks (k,q,v).
// ---------------------------------------------------------------------------
__global__ __launch_bounds__(256, 2) void prep_w(
    const float* __restrict__ Wk, const float* __restrict__ Wq,
    const float* __restrict__ Wv,
    unsigned short* __restrict__ wt_hi, unsigned short* __restrict__ wt_lo)
{
  __shared__ unsigned short hbuf[64][66];
  __shared__ unsigned short lbuf[64][66];
  const int m = (int)blockIdx.x;
  const float* Wm = (m == 0) ? Wk : (m == 1 ? Wq : Wv);
  const int tid = (int)threadIdx.x;
  for (int idx = tid; idx < 1024; idx += 256) {
    int c = idx >> 4, o4 = (idx & 15) * 4;
    float4 v = *(const float4*)(Wm + c * 64 + o4);
    float vals[4] = {v.x, v.y, v.z, v.w};
#pragma unroll
    for (int j = 0; j < 4; ++j) {
      unsigned short h = f2bf(vals[j]);
      hbuf[o4 + j][c] = h;
      lbuf[o4 + j][c] = f2bf(vals[j] - bf2f(h));
    }
  }
  __syncthreads();
  for (int idx = tid; idx < 1024; idx += 256) {
    int o = idx >> 4, c0 = (idx & 15) * 4;
    ushort4 hv, lv;
    hv.x = hbuf[o][c0]; hv.y = hbuf[o][c0 + 1];
    hv.z = hbuf[o][c0 + 2]; hv.w = hbuf[o][c0 + 3];
    lv.x = lbuf[o][c0]; lv.y = lbuf[o][c0 + 1];
    lv.z = lbuf[o][c0 + 2]; lv.w = lbuf[o][c0 + 3];
    *(ushort4*)(wt_hi + (size_t)(m * 64 + o) * 64 + c0) = hv;
    *(ushort4*)(wt_lo + (size_t)(m * 64 + o) * 64 + c0) = lv;
  }
}

// ---------------------------------------------------------------------------
// Kernel 1: q,k,v projections. 64 rows per block. (r13 validated)
// ---------------------------------------------------------------------------
__global__ __launch_bounds__(256, 2) void proj_kernel(
    const float* __restrict__ x,
    const unsigned short* __restrict__ wt_hi, const unsigned short* __restrict__ wt_lo,
    const float* __restrict__ bk, const float* __restrict__ bq, const float* __restrict__ bv,
    unsigned short* __restrict__ khi, unsigned short* __restrict__ klo,
    unsigned short* __restrict__ qhi, unsigned short* __restrict__ qlo,
    unsigned short* __restrict__ vt)
{
  __shared__ __align__(16) char smem[65536];
  const int XH = 0, XL = 8192, WTH = 16384, WTL = 40960, VTB = 0; // VTB aliases XH
  const int tid = (int)threadIdx.x;
  const int l = tid & 63, w = tid >> 6;
  const int lr = l & 15, lg = l >> 4;
  const int blk = (int)blockIdx.x;
  const int rowbase = blk * 64;
  const int bb = blk >> 5;          // 32 blocks per batch

  // issue ALL x loads first (4 float4/thread in flight)
  float4 xv[4];
#pragma unroll
  for (int j = 0; j < 4; ++j) {
    int c = tid + j * 256;
    int row = c >> 4, d0 = (c & 15) * 4;
    xv[j] = *(const float4*)(x + (size_t)(rowbase + row) * NC + d0);
  }
  // stage W^T hi/lo (24 KB each) via global_load_lds, pre-swizzled source
#pragma unroll
  for (int ch4 = 0; ch4 < 6; ++ch4) {
    int ch = ch4 * 4 + w;           // 24 chunks of 1KB per region
    int d = ch * 1024 + l * 16;
    int swk = d ^ (((d >> 7) & 7) << 4);
    GLD_LDS16((const char*)wt_hi + swk, smem + WTH + ch * 1024);
    GLD_LDS16((const char*)wt_lo + swk, smem + WTL + ch * 1024);
  }
  // convert + write x tile (64x64) as hi/lo bf16, swizzled
#pragma unroll
  for (int j = 0; j < 4; ++j) {
    int c = tid + j * 256;
    int row = c >> 4, d0 = (c & 15) * 4;
    unsigned short h0 = f2bf(xv[j].x), h1 = f2bf(xv[j].y), h2 = f2bf(xv[j].z), h3 = f2bf(xv[j].w);
    unsigned short m0 = f2bf(xv[j].x - bf2f(h0)), m1 = f2bf(xv[j].y - bf2f(h1));
    unsigned short m2 = f2bf(xv[j].z - bf2f(h2)), m3 = f2bf(xv[j].w - bf2f(h3));
    uint2 ph, pl;
    ph.x = (uint32_t)h0 | ((uint32_t)h1 << 16); ph.y = (uint32_t)h2 | ((uint32_t)h3 << 16);
    pl.x = (uint32_t)m0 | ((uint32_t)m1 << 16); pl.y = (uint32_t)m2 | ((uint32_t)m3 << 16);
    int byteoff = (row * 128 + d0 * 2) ^ ((row & 7) << 4);
    *(uint2*)(smem + XH + byteoff) = ph;
    *(uint2*)(smem + XL + byteoff) = pl;
  }
  __syncthreads();

  // x B-frags for this wave's 16 rows (t = w*16 + lr)
  bf16x8 xh[2], xl[2];
  {
    int row = w * 16 + lr;
#pragma unroll
    for (int dc = 0; dc < 2; ++dc) {
      int byteoff = (row * 128 + (dc * 32 + lg * 8) * 2) ^ ((row & 7) << 4);
      xh[dc] = *(const bf16x8*)(smem + XH + byteoff);
      xl[dc] = *(const bf16x8*)(smem + XL + byteoff);
    }
  }
  // A = W^T (rows og -> C reg dim), B = x (rows t -> C lane dim)
  f32x4 acc[12];
#pragma unroll
  for (int nb = 0; nb < 12; ++nb) {
    f32x4 a = {0.f, 0.f, 0.f, 0.f};
    int og = nb * 16 + lr;
#pragma unroll
    for (int dc = 0; dc < 2; ++dc) {
      int byteoff = (og * 128 + (dc * 32 + lg * 8) * 2) ^ ((og & 7) << 4);
      bf16x8 bh = *(const bf16x8*)(smem + WTH + byteoff);
      bf16x8 bl = *(const bf16x8*)(smem + WTL + byteoff);
      a = __builtin_amdgcn_mfma_f32_16x16x32_bf16(bh, xh[dc], a, 0, 0, 0);
      a = __builtin_amdgcn_mfma_f32_16x16x32_bf16(bl, xh[dc], a, 0, 0, 0);
      a = __builtin_amdgcn_mfma_f32_16x16x32_bf16(bh, xl[dc], a, 0, 0, 0);
    }
    acc[nb] = a;
  }
  __syncthreads();  // done reading XH/XL; VTB may now alias

  // epilogue: lane holds t = w*16+lr, og = nb*16 + lg*4 + r (4 consecutive)
  const int tloc = w * 16 + lr;
  const size_t gt = (size_t)(rowbase + tloc);
#pragma unroll
  for (int nb = 0; nb < 12; ++nb) {
    int ogb = (nb & 3) * 16 + lg * 4;
    const float* bp = (nb < 4) ? bk : (nb < 8 ? bq : bv);
    float4 bias = *(const float4*)(bp + ogb);
    float v0 = acc[nb][0] + bias.x, v1 = acc[nb][1] + bias.y,
          v2 = acc[nb][2] + bias.z, v3 = acc[nb][3] + bias.w;
    if (nb < 8) {
      if (nb >= 4) { v0 *= SC_LOG2E; v1 *= SC_LOG2E; v2 *= SC_LOG2E; v3 *= SC_LOG2E; }
      ushort4 hv, lv;
      hv.x = f2bf(v0); lv.x = f2bf(v0 - bf2f(hv.x));
      hv.y = f2bf(v1); lv.y = f2bf(v1 - bf2f(hv.y));
      hv.z = f2bf(v2); lv.z = f2bf(v2 - bf2f(hv.z));
      hv.w = f2bf(v3); lv.w = f2bf(v3 - bf2f(hv.w));
      unsigned short* dH = (nb < 4) ? khi : qhi;
      unsigned short* dL = (nb < 4) ? klo : qlo;
      *(ushort4*)(dH + gt * 64 + ogb) = hv;
      *(ushort4*)(dL + gt * 64 + ogb) = lv;
    } else {
      float vs[4] = {v0, v1, v2, v3};
#pragma unroll
      for (int r = 0; r < 4; ++r) {
        int o = ogb + r;
        int byteoff = (o * 128 + tloc * 2) ^ ((o & 7) << 4);
        *(unsigned short*)(smem + VTB + byteoff) = f2bf(vs[r]);
      }
    }
  }
  __syncthreads();
  for (int cc = tid; cc < 512; cc += 256) {
    int o = cc >> 3, t0 = (cc & 7) * 8;
    int byteoff = (o * 128 + t0 * 2) ^ ((o & 7) << 4);
    uint4 v = *(const uint4*)(smem + VTB + byteoff);
    *(uint4*)(vt + ((size_t)bb * 64 + o) * NT + (size_t)(blk & 31) * 64 + t0) = v;
  }
}

// ---------------------------------------------------------------------------
// Kernel 2: flash attention — round-4 validated 512-thread structure
// (8 waves = 4 q-groups x 2 key-halves) + 6 independent QK^T MFMA chains
// (register budget at 512 thr permits) + permlane32_swap exchanges (r7).
// ---------------------------------------------------------------------------
__global__ __launch_bounds__(512, 2) void attn_kernel(
    const unsigned short* __restrict__ khi, const unsigned short* __restrict__ klo,
    const unsigned short* __restrict__ qhi, const unsigned short* __restrict__ qlo,
    const unsigned short* __restrict__ vt,
    float* __restrict__ out)
{
  __shared__ __align__(16) char smem[98304];
  const int BUF = 49152;   // per-buffer: KHI 16K | KLO 16K | VT 16K
  const int MLB = 65536;   // epilogue m/l exchange (inside buf1; used post-loop)
  const int tid = (int)threadIdx.x;
  const int l = tid & 63, w = tid >> 6;     // w in 0..7
  const int lq = l & 31;
  const bool hi = (l >= 32);
  const int hioff = hi ? 16 : 0;
  const int r = w & 3;                      // q-group: rows 32r..32r+31
  const int cc = w >> 2;                    // key half: keys 64cc..64cc+63
  const int lb = ((int)(blockIdx.x & 7) << 5) | ((int)blockIdx.x >> 3);
  const int bb = lb >> 4;
  const int qt = lb & 15;

  const char* kh_base = (const char*)(khi + (size_t)bb * NT * 64);
  const char* kl_base = (const char*)(klo + (size_t)bb * NT * 64);
  const char* v_base  = (const char*)(vt + (size_t)bb * 64 * NT);

#define STAGE_TILE(bufp_, it_)                                                 \
  do {                                                                         \
    const char* kh_t = kh_base + (size_t)(it_) * 16384;                        \
    const char* kl_t = kl_base + (size_t)(it_) * 16384;                        \
    const char* v_tb = v_base + (size_t)(it_) * 256;                           \
    _Pragma("unroll")                                                          \
    for (int j = 0; j < 2; ++j) {                                              \
      int ch = 2 * w + j;                                                      \
      int d = ch * 1024 + l * 16;                                              \
      int swk = d ^ (((d >> 7) & 7) << 4);                                     \
      GLD_LDS16(kh_t + swk, (bufp_) + ch * 1024);                              \
      GLD_LDS16(kl_t + swk, (bufp_) + 16384 + ch * 1024);                      \
      int o = d >> 8;                                                          \
      int swv = (d ^ ((o & 7) << 4)) & 255;                                    \
      GLD_LDS16(v_tb + (size_t)o * 4096 + swv, (bufp_) + 32768 + ch * 1024);   \
    }                                                                          \
  } while (0)

  // prologue: stage tile 0; load Q fragments (rows 32r..32r+31, B-operand)
  STAGE_TILE(smem, 0);
  bf16x8 Qh[4], Ql[4];
  {
    const char* qh_t = (const char*)qhi + ((size_t)bb * NT + (size_t)qt * QT) * 128;
    const char* ql_t = (const char*)qlo + ((size_t)bb * NT + (size_t)qt * QT) * 128;
    int qrow = r * 32 + lq;
#pragma unroll
    for (int dc = 0; dc < 4; ++dc) {
      Qh[dc] = *(const bf16x8*)(qh_t + qrow * 128 + dc * 32 + hioff);
      Ql[dc] = *(const bf16x8*)(ql_t + qrow * 128 + dc * 32 + hioff);
    }
  }
  asm volatile("s_waitcnt vmcnt(0)" ::: "memory");
  __builtin_amdgcn_s_barrier();
  asm volatile("" ::: "memory");

  f32x16 O0 = Z16, O1 = Z16;
  float mrun = -1e30f, lrun = 0.f;
  const int swr = (lq & 7) << 4;

  for (int it = 0; it < NT / KT; ++it) {
    char* cb = smem + (it & 1) * BUF;
    if (it + 1 < NT / KT) STAGE_TILE(smem + ((it + 1) & 1) * BUF, it + 1);

    // --- S^T[key][q] = K · Q^T: 6 INDEPENDENT chains (depth 4 each)
    f32x16 T1a = Z16, T2a = Z16, T3a = Z16;
    f32x16 T1b = Z16, T2b = Z16, T3b = Z16;
    __builtin_amdgcn_s_setprio(1);
    {
      int row0 = cc * 64 + lq;
      int row1 = row0 + 32;
#pragma unroll
      for (int dc = 0; dc < 4; ++dc) {
        int cchunk = (dc * 32 + hioff) ^ swr;   // (row&7)==(lq&7) for both rows
        bf16x8 Ah0 = *(const bf16x8*)(cb + row0 * 128 + cchunk);
        bf16x8 Al0 = *(const bf16x8*)(cb + 16384 + row0 * 128 + cchunk);
        bf16x8 Ah1 = *(const bf16x8*)(cb + row1 * 128 + cchunk);
        bf16x8 Al1 = *(const bf16x8*)(cb + 16384 + row1 * 128 + cchunk);
        T1a = __builtin_amdgcn_mfma_f32_32x32x16_bf16(Ah0, Qh[dc], T1a, 0, 0, 0);
        T1b = __builtin_amdgcn_mfma_f32_32x32x16_bf16(Ah1, Qh[dc], T1b, 0, 0, 0);
        T2a = __builtin_amdgcn_mfma_f32_32x32x16_bf16(Al0, Qh[dc], T2a, 0, 0, 0);
        T2b = __builtin_amdgcn_mfma_f32_32x32x16_bf16(Al1, Qh[dc], T2b, 0, 0, 0);
        T3a = __builtin_amdgcn_mfma_f32_32x32x16_bf16(Ah0, Ql[dc], T3a, 0, 0, 0);
        T3b = __builtin_amdgcn_mfma_f32_32x32x16_bf16(Ah1, Ql[dc], T3b, 0, 0, 0);
      }
    }
    __builtin_amdgcn_s_setprio(0);
    f32x16 S0 = (T1a + T2a) + T3a;
    f32x16 S1 = (T1b + T2b) + T3b;

    // --- online softmax over 32 keys (per-lane q); permlane cross-half reduce
    float m01 = fmaxf(S0[0], S0[1]),   m23 = fmaxf(S0[2], S0[3]);
    float m45 = fmaxf(S0[4], S0[5]),   m67 = fmaxf(S0[6], S0[7]);
    float m89 = fmaxf(S0[8], S0[9]),   mab = fmaxf(S0[10], S0[11]);
    float mcd = fmaxf(S0[12], S0[13]), mef = fmaxf(S0[14], S0[15]);
    float pmax = fmaxf(fmaxf(fmaxf(m01, m23), fmaxf(m45, m67)),
                       fmaxf(fmaxf(m89, mab), fmaxf(mcd, mef)));
    m01 = fmaxf(S1[0], S1[1]);   m23 = fmaxf(S1[2], S1[3]);
    m45 = fmaxf(S1[4], S1[5]);   m67 = fmaxf(S1[6], S1[7]);
    m89 = fmaxf(S1[8], S1[9]);   mab = fmaxf(S1[10], S1[11]);
    mcd = fmaxf(S1[12], S1[13]); mef = fmaxf(S1[14], S1[15]);
    pmax = fmaxf(pmax, fmaxf(fmaxf(fmaxf(m01, m23), fmaxf(m45, m67)),
                             fmaxf(fmaxf(m89, mab), fmaxf(mcd, mef))));
    {
      auto sw = __builtin_amdgcn_permlane32_swap(uasf(pmax), uasf(pmax), false, false);
      pmax = fmaxf(fasu(sw[0]), fasu(sw[1]));
    }
    if (__any(pmax > mrun + 11.55f)) {      // defer-max (e^1 logit window)
      float mnew = fmaxf(mrun, pmax);
      float alpha = __ocml_exp2_f32(mrun - mnew);
      O0 *= alpha; O1 *= alpha; lrun *= alpha; mrun = mnew;
    }
    float p0[16], p1[16];
    float ts = 0.f;
#pragma unroll
    for (int i = 0; i < 16; ++i) { p0[i] = __ocml_exp2_f32(S0[i] - mrun); ts += p0[i]; }
#pragma unroll
    for (int i = 0; i < 16; ++i) { p1[i] = __ocml_exp2_f32(S1[i] - mrun); ts += p1[i]; }
    {
      auto sw = __builtin_amdgcn_permlane32_swap(uasf(ts), uasf(ts), false, false);
      ts = fasu(sw[0]) + fasu(sw[1]);
    }
    lrun += ts;

    // --- O^T += V^T · P^T  (A = V^T frag from LDS, B = P^T in-register)
#define PV_CHUNK(kc_, PARR)                                                    \
    {                                                                          \
      const int b_ = 8 * ((kc_) & 1);                                          \
      uint32_t X0, X1, Y0, Y1;                                                 \
      asm("v_cvt_pk_bf16_f32 %0, %1, %2" : "=v"(X0) : "v"(PARR[b_+0]), "v"(PARR[b_+1])); \
      asm("v_cvt_pk_bf16_f32 %0, %1, %2" : "=v"(X1) : "v"(PARR[b_+2]), "v"(PARR[b_+3])); \
      asm("v_cvt_pk_bf16_f32 %0, %1, %2" : "=v"(Y0) : "v"(PARR[b_+4]), "v"(PARR[b_+5])); \
      asm("v_cvt_pk_bf16_f32 %0, %1, %2" : "=v"(Y1) : "v"(PARR[b_+6]), "v"(PARR[b_+7])); \
      auto sw0 = __builtin_amdgcn_permlane32_swap(X0, Y0, false, false);       \
      auto sw1 = __builtin_amdgcn_permlane32_swap(X1, Y1, false, false);       \
      union { uint32_t u[4]; bf16x8 v; } cvb;                                  \
      cvb.u[0] = sw0[0]; cvb.u[1] = sw1[0];                                    \
      cvb.u[2] = sw0[1]; cvb.u[3] = sw1[1];                                    \
      bf16x8 Bp = cvb.v;                                                       \
      int vcol = 128 * cc + 32 * (kc_) + hioff;                                \
      {                                                                        \
        bf16x8 Av = *(const bf16x8*)(cb + 32768 + lq * 256 + (vcol ^ swr));    \
        O0 = __builtin_amdgcn_mfma_f32_32x32x16_bf16(Av, Bp, O0, 0, 0, 0);     \
      }                                                                        \
      {                                                                        \
        bf16x8 Av = *(const bf16x8*)(cb + 32768 + (32 + lq) * 256 + (vcol ^ swr)); \
        O1 = __builtin_amdgcn_mfma_f32_32x32x16_bf16(Av, Bp, O1, 0, 0, 0);     \
      }                                                                        \
    }
    __builtin_amdgcn_s_setprio(1);
    PV_CHUNK(0, p0)
    PV_CHUNK(1, p0)
    PV_CHUNK(2, p1)
    PV_CHUNK(3, p1)
    __builtin_amdgcn_s_setprio(0);
#undef PV_CHUNK

    // tail: drain next tile's loads (flew during compute), then publish
    asm volatile("s_waitcnt vmcnt(0)" ::: "memory");
    __builtin_amdgcn_s_barrier();
    asm volatile("" ::: "memory");
    __builtin_amdgcn_sched_barrier(0);
  }

  // --- epilogue: merge key halves (cc=1 -> cc=0), direct f32x4 stores
  const int lsw = (l & 7) << 4;
  if (cc == 1) {
    char* dd = smem + r * 8192 + l * 128;
#pragma unroll
    for (int g = 0; g < 4; ++g) {
      f32x4 t0, t1;
#pragma unroll
      for (int j = 0; j < 4; ++j) { t0[j] = O0[4*g+j]; t1[j] = O1[4*g+j]; }
      *(f32x4*)(dd + ((g * 16) ^ lsw)) = t0;
      *(f32x4*)(dd + ((64 + g * 16) ^ lsw)) = t1;
    }
    *(float*)(smem + MLB + r * 256 + lq * 8) = mrun;
    *(float*)(smem + MLB + r * 256 + lq * 8 + 4) = lrun;
  }
  __syncthreads();
  if (cc == 0) {
    const char* ds = smem + r * 8192 + l * 128;
    float m1 = *(const float*)(smem + MLB + r * 256 + lq * 8);
    float l1 = *(const float*)(smem + MLB + r * 256 + lq * 8 + 4);
    float M = fmaxf(mrun, m1);
    float a0 = __ocml_exp2_f32(mrun - M);
    float a1 = __ocml_exp2_f32(m1 - M);
    float Lt = lrun * a0 + l1 * a1;
    float inv = 1.0f / Lt;
    float f0 = a0 * inv, f1 = a1 * inv;
    float* orow = out + ((size_t)bb * NT + (size_t)qt * QT + r * 32 + lq) * 64;
#pragma unroll
    for (int g = 0; g < 4; ++g) {
      f32x4 o1a = *(const f32x4*)(ds + ((g * 16) ^ lsw));
      f32x4 o1b = *(const f32x4*)(ds + ((64 + g * 16) ^ lsw));
      int d0 = 8 * g + (hi ? 4 : 0);
      f32x4 s0, s1;
#pragma unroll
      for (int j = 0; j < 4; ++j) {
        s0[j] = O0[4*g+j] * f0 + o1a[j] * f1;
        s1[j] = O1[4*g+j] * f0 + o1b[j] * f1;
      }
      *(f32x4*)(orow + d0) = s0;
      *(f32x4*)(orow + d0 + 32) = s1;
    }
  }
#undef STAGE_TILE
}

extern "C" void kernel_launch(void* const* d_in, const int* in_sizes, int n_in,
                              void* d_out, int out_size, void* d_ws, size_t ws_size,
                              hipStream_t stream) {
  const float* x  = (const float*)d_in[0];
  const float* Wk = (const float*)d_in[1];
  const float* bk = (const float*)d_in[2];
  const float* Wq = (const float*)d_in[3];
  const float* bq = (const float*)d_in[4];
  const float* Wv = (const float*)d_in[5];
  const float* bv = (const float*)d_in[6];
  float* out = (float*)d_out;

  const size_t NE = (size_t)NBATCH * NT * 64;
  unsigned short* ws = (unsigned short*)d_ws;
  unsigned short* khi = ws;
  unsigned short* klo = ws + NE;
  unsigned short* qhi = ws + 2 * NE;
  unsigned short* qlo = ws + 3 * NE;
  unsigned short* vt  = ws + 4 * NE;
  unsigned short* wt_hi = ws + 5 * NE;
  unsigned short* wt_lo = wt_hi + 192 * 64;

  prep_w<<<dim3(3), dim3(256), 0, stream>>>(Wk, Wq, Wv, wt_hi, wt_lo);
  proj_kernel<<<dim3((NBATCH * NT) / 64), dim3(256), 0, stream>>>(
      x, wt_hi, wt_lo, bk, bq, bv, khi, klo, qhi, qlo, vt);
  attn_kernel<<<dim3(NBATCH * (NT / QT)), dim3(512), 0, stream>>>(
      khi, klo, qhi, qlo, vt, out);
}

// Round 16
// 67.340 us; speedup vs baseline: 1.3090x; 1.1101x over previous
//
#include <hip/hip_runtime.h>
#include <hip/hip_bf16.h>
#include <stdint.h>

#define NBATCH 16
#define NT 2048
#define NC 64
#define QT 128
#define KT 128
#define SC_LOG2E 11.5415603f  // 8 * log2(e)

typedef __bf16 bf16x8 __attribute__((ext_vector_type(8)));
typedef float f32x4 __attribute__((ext_vector_type(4)));
typedef float f32x16 __attribute__((ext_vector_type(16)));

#define Z16 {0.f,0.f,0.f,0.f,0.f,0.f,0.f,0.f,0.f,0.f,0.f,0.f,0.f,0.f,0.f,0.f}

extern "C" __device__ float __ocml_native_exp2_f32(float);
#define EXP2F(x) __ocml_native_exp2_f32(x)

static __device__ __forceinline__ unsigned short f2bf(float f) {
  __bf16 h = (__bf16)f;  // hardware RTNE convert
  union { __bf16 h; unsigned short u; } a; a.h = h; return a.u;
}
static __device__ __forceinline__ float bf2f(unsigned short h) {
  union { uint32_t u; float f; } a; a.u = ((uint32_t)h) << 16;
  return a.f;
}
static __device__ __forceinline__ float fasu(uint32_t u) {
  union { uint32_t u; float f; } a; a.u = u; return a.f;
}
static __device__ __forceinline__ uint32_t uasf(float f) {
  union { float f; uint32_t u; } a; a.f = f; return a.u;
}

#define GLD_LDS16(gsrc, ldst)                                                  \
  __builtin_amdgcn_global_load_lds(                                            \
      (const __attribute__((address_space(1))) void*)(gsrc),                   \
      (__attribute__((address_space(3))) void*)(ldst), 16, 0, 0)

// ---------------------------------------------------------------------------
// Kernel 0: one-time W transpose + hi/lo bf16 split. 3 blocks (k,q,v).
// ---------------------------------------------------------------------------
__global__ __launch_bounds__(256, 2) void prep_w(
    const float* __restrict__ Wk, const float* __restrict__ Wq,
    const float* __restrict__ Wv,
    unsigned short* __restrict__ wt_hi, unsigned short* __restrict__ wt_lo)
{
  __shared__ unsigned short hbuf[64][66];
  __shared__ unsigned short lbuf[64][66];
  const int m = (int)blockIdx.x;
  const float* Wm = (m == 0) ? Wk : (m == 1 ? Wq : Wv);
  const int tid = (int)threadIdx.x;
  for (int idx = tid; idx < 1024; idx += 256) {
    int c = idx >> 4, o4 = (idx & 15) * 4;
    float4 v = *(const float4*)(Wm + c * 64 + o4);
    float vals[4] = {v.x, v.y, v.z, v.w};
#pragma unroll
    for (int j = 0; j < 4; ++j) {
      unsigned short h = f2bf(vals[j]);
      hbuf[o4 + j][c] = h;
      lbuf[o4 + j][c] = f2bf(vals[j] - bf2f(h));
    }
  }
  __syncthreads();
  for (int idx = tid; idx < 1024; idx += 256) {
    int o = idx >> 4, c0 = (idx & 15) * 4;
    ushort4 hv, lv;
    hv.x = hbuf[o][c0]; hv.y = hbuf[o][c0 + 1];
    hv.z = hbuf[o][c0 + 2]; hv.w = hbuf[o][c0 + 3];
    lv.x = lbuf[o][c0]; lv.y = lbuf[o][c0 + 1];
    lv.z = lbuf[o][c0 + 2]; lv.w = lbuf[o][c0 + 3];
    *(ushort4*)(wt_hi + (size_t)(m * 64 + o) * 64 + c0) = hv;
    *(ushort4*)(wt_lo + (size_t)(m * 64 + o) * 64 + c0) = lv;
  }
}

// ---------------------------------------------------------------------------
// Kernel 1: q,k,v projections. 64 rows per block. (r13 validated)
// ---------------------------------------------------------------------------
__global__ __launch_bounds__(256, 2) void proj_kernel(
    const float* __restrict__ x,
    const unsigned short* __restrict__ wt_hi, const unsigned short* __restrict__ wt_lo,
    const float* __restrict__ bk, const float* __restrict__ bq, const float* __restrict__ bv,
    unsigned short* __restrict__ khi, unsigned short* __restrict__ klo,
    unsigned short* __restrict__ qhi, unsigned short* __restrict__ qlo,
    unsigned short* __restrict__ vt)
{
  __shared__ __align__(16) char smem[65536];
  const int XH = 0, XL = 8192, WTH = 16384, WTL = 40960, VTB = 0; // VTB aliases XH
  const int tid = (int)threadIdx.x;
  const int l = tid & 63, w = tid >> 6;
  const int lr = l & 15, lg = l >> 4;
  const int blk = (int)blockIdx.x;
  const int rowbase = blk * 64;
  const int bb = blk >> 5;          // 32 blocks per batch

  // issue ALL x loads first (4 float4/thread in flight)
  float4 xv[4];
#pragma unroll
  for (int j = 0; j < 4; ++j) {
    int c = tid + j * 256;
    int row = c >> 4, d0 = (c & 15) * 4;
    xv[j] = *(const float4*)(x + (size_t)(rowbase + row) * NC + d0);
  }
  // stage W^T hi/lo (24 KB each) via global_load_lds, pre-swizzled source
#pragma unroll
  for (int ch4 = 0; ch4 < 6; ++ch4) {
    int ch = ch4 * 4 + w;           // 24 chunks of 1KB per region
    int d = ch * 1024 + l * 16;
    int swk = d ^ (((d >> 7) & 7) << 4);
    GLD_LDS16((const char*)wt_hi + swk, smem + WTH + ch * 1024);
    GLD_LDS16((const char*)wt_lo + swk, smem + WTL + ch * 1024);
  }
  // convert + write x tile (64x64) as hi/lo bf16, swizzled
#pragma unroll
  for (int j = 0; j < 4; ++j) {
    int c = tid + j * 256;
    int row = c >> 4, d0 = (c & 15) * 4;
    unsigned short h0 = f2bf(xv[j].x), h1 = f2bf(xv[j].y), h2 = f2bf(xv[j].z), h3 = f2bf(xv[j].w);
    unsigned short m0 = f2bf(xv[j].x - bf2f(h0)), m1 = f2bf(xv[j].y - bf2f(h1));
    unsigned short m2 = f2bf(xv[j].z - bf2f(h2)), m3 = f2bf(xv[j].w - bf2f(h3));
    uint2 ph, pl;
    ph.x = (uint32_t)h0 | ((uint32_t)h1 << 16); ph.y = (uint32_t)h2 | ((uint32_t)h3 << 16);
    pl.x = (uint32_t)m0 | ((uint32_t)m1 << 16); pl.y = (uint32_t)m2 | ((uint32_t)m3 << 16);
    int byteoff = (row * 128 + d0 * 2) ^ ((row & 7) << 4);
    *(uint2*)(smem + XH + byteoff) = ph;
    *(uint2*)(smem + XL + byteoff) = pl;
  }
  __syncthreads();

  // x B-frags for this wave's 16 rows (t = w*16 + lr)
  bf16x8 xh[2], xl[2];
  {
    int row = w * 16 + lr;
#pragma unroll
    for (int dc = 0; dc < 2; ++dc) {
      int byteoff = (row * 128 + (dc * 32 + lg * 8) * 2) ^ ((row & 7) << 4);
      xh[dc] = *(const bf16x8*)(smem + XH + byteoff);
      xl[dc] = *(const bf16x8*)(smem + XL + byteoff);
    }
  }
  // A = W^T (rows og -> C reg dim), B = x (rows t -> C lane dim)
  f32x4 acc[12];
#pragma unroll
  for (int nb = 0; nb < 12; ++nb) {
    f32x4 a = {0.f, 0.f, 0.f, 0.f};
    int og = nb * 16 + lr;
#pragma unroll
    for (int dc = 0; dc < 2; ++dc) {
      int byteoff = (og * 128 + (dc * 32 + lg * 8) * 2) ^ ((og & 7) << 4);
      bf16x8 bh = *(const bf16x8*)(smem + WTH + byteoff);
      bf16x8 bl = *(const bf16x8*)(smem + WTL + byteoff);
      a = __builtin_amdgcn_mfma_f32_16x16x32_bf16(bh, xh[dc], a, 0, 0, 0);
      a = __builtin_amdgcn_mfma_f32_16x16x32_bf16(bl, xh[dc], a, 0, 0, 0);
      a = __builtin_amdgcn_mfma_f32_16x16x32_bf16(bh, xl[dc], a, 0, 0, 0);
    }
    acc[nb] = a;
  }
  __syncthreads();  // done reading XH/XL; VTB may now alias

  // epilogue: lane holds t = w*16+lr, og = nb*16 + lg*4 + r (4 consecutive)
  const int tloc = w * 16 + lr;
  const size_t gt = (size_t)(rowbase + tloc);
#pragma unroll
  for (int nb = 0; nb < 12; ++nb) {
    int ogb = (nb & 3) * 16 + lg * 4;
    const float* bp = (nb < 4) ? bk : (nb < 8 ? bq : bv);
    float4 bias = *(const float4*)(bp + ogb);
    float v0 = acc[nb][0] + bias.x, v1 = acc[nb][1] + bias.y,
          v2 = acc[nb][2] + bias.z, v3 = acc[nb][3] + bias.w;
    if (nb < 8) {
      if (nb >= 4) { v0 *= SC_LOG2E; v1 *= SC_LOG2E; v2 *= SC_LOG2E; v3 *= SC_LOG2E; }
      ushort4 hv, lv;
      hv.x = f2bf(v0); lv.x = f2bf(v0 - bf2f(hv.x));
      hv.y = f2bf(v1); lv.y = f2bf(v1 - bf2f(hv.y));
      hv.z = f2bf(v2); lv.z = f2bf(v2 - bf2f(hv.z));
      hv.w = f2bf(v3); lv.w = f2bf(v3 - bf2f(hv.w));
      unsigned short* dH = (nb < 4) ? khi : qhi;
      unsigned short* dL = (nb < 4) ? klo : qlo;
      *(ushort4*)(dH + gt * 64 + ogb) = hv;
      *(ushort4*)(dL + gt * 64 + ogb) = lv;
    } else {
      float vs[4] = {v0, v1, v2, v3};
#pragma unroll
      for (int r = 0; r < 4; ++r) {
        int o = ogb + r;
        int byteoff = (o * 128 + tloc * 2) ^ ((o & 7) << 4);
        *(unsigned short*)(smem + VTB + byteoff) = f2bf(vs[r]);
      }
    }
  }
  __syncthreads();
  for (int cc = tid; cc < 512; cc += 256) {
    int o = cc >> 3, t0 = (cc & 7) * 8;
    int byteoff = (o * 128 + t0 * 2) ^ ((o & 7) << 4);
    uint4 v = *(const uint4*)(smem + VTB + byteoff);
    *(uint4*)(vt + ((size_t)bb * 64 + o) * NT + (size_t)(blk & 31) * 64 + t0) = v;
  }
}

// ---------------------------------------------------------------------------
// Kernel 2: flash attention — round-10 kernel (54.4 us validated) with ONE
// change: __ocml_exp2_f32 -> __ocml_native_exp2_f32 (bare v_exp_f32; the
// libm wrapper's overflow/denormal guards were the suspected VALU bloat).
// ---------------------------------------------------------------------------
__global__ __launch_bounds__(1024, 4) void attn_kernel(
    const unsigned short* __restrict__ khi, const unsigned short* __restrict__ klo,
    const unsigned short* __restrict__ qhi, const unsigned short* __restrict__ qlo,
    const unsigned short* __restrict__ vt,
    float* __restrict__ out)
{
  __shared__ __align__(16) char smem[98304];
  const int BUF = 49152;   // per-buffer: KHI 16K | KLO 16K | VT 16K
  const int MLB = 65536;   // epilogue m/l exchange (aliases buf space)
  const int tid = (int)threadIdx.x;
  const int l = tid & 63, w = tid >> 6;     // w in 0..15
  const int lq = l & 31;
  const bool hi = (l >= 32);
  const int hioff = hi ? 16 : 0;
  const int r = w & 3;                      // q-group: rows 32r..32r+31
  const int cc = w >> 2;                    // key quarter: keys 32cc..32cc+31
  const int lb = ((int)(blockIdx.x & 7) << 5) | ((int)blockIdx.x >> 3);
  const int bb = lb >> 4;
  const int qt = lb & 15;

  const char* kh_base = (const char*)(khi + (size_t)bb * NT * 64);
  const char* kl_base = (const char*)(klo + (size_t)bb * NT * 64);
  const char* v_base  = (const char*)(vt + (size_t)bb * 64 * NT);

#define STAGE_TILE(bufp_, it_)                                                 \
  do {                                                                         \
    const char* kh_t = kh_base + (size_t)(it_) * 16384;                        \
    const char* kl_t = kl_base + (size_t)(it_) * 16384;                        \
    const char* v_tb = v_base + (size_t)(it_) * 256;                           \
    int d_ = w * 1024 + l * 16;                                                \
    int swk_ = d_ ^ (((d_ >> 7) & 7) << 4);                                    \
    GLD_LDS16(kh_t + swk_, (bufp_) + w * 1024);                                \
    GLD_LDS16(kl_t + swk_, (bufp_) + 16384 + w * 1024);                        \
    int o_ = d_ >> 8;                                                          \
    int swv_ = (d_ & 255) ^ ((o_ & 7) << 4);                                   \
    GLD_LDS16(v_tb + (size_t)o_ * 4096 + swv_, (bufp_) + 32768 + w * 1024);    \
  } while (0)

  // prologue: stage tile 0; load Q fragments (rows 32r..32r+31, B-operand)
  STAGE_TILE(smem, 0);
  bf16x8 Qh[4], Ql[4];
  {
    const char* qh_t = (const char*)qhi + ((size_t)bb * NT + (size_t)qt * QT) * 128;
    const char* ql_t = (const char*)qlo + ((size_t)bb * NT + (size_t)qt * QT) * 128;
    int qrow = r * 32 + lq;
#pragma unroll
    for (int dc = 0; dc < 4; ++dc) {
      Qh[dc] = *(const bf16x8*)(qh_t + qrow * 128 + dc * 32 + hioff);
      Ql[dc] = *(const bf16x8*)(ql_t + qrow * 128 + dc * 32 + hioff);
    }
  }
  asm volatile("s_waitcnt vmcnt(0)" ::: "memory");
  __builtin_amdgcn_s_barrier();
  asm volatile("" ::: "memory");

  f32x16 O0 = Z16, O1 = Z16;
  float mrun = -1e30f, lrun = 0.f;
  const int swr = (lq & 7) << 4;

  for (int it = 0; it < NT / KT; ++it) {
    char* cb = smem + (it & 1) * BUF;
    if (it + 1 < NT / KT) STAGE_TILE(smem + ((it + 1) & 1) * BUF, it + 1);

    // --- S^T[key][q] = K · Q^T (3-term hi/lo), single accumulator chain
    f32x16 S = Z16;
    __builtin_amdgcn_s_setprio(1);
#pragma unroll
    for (int dc = 0; dc < 4; ++dc) {
      int krow = cc * 32 + lq;
      int cchunk = (dc * 32 + hioff) ^ swr;
      bf16x8 Ah = *(const bf16x8*)(cb + krow * 128 + cchunk);
      bf16x8 Al = *(const bf16x8*)(cb + 16384 + krow * 128 + cchunk);
      S = __builtin_amdgcn_mfma_f32_32x32x16_bf16(Ah, Qh[dc], S, 0, 0, 0);
      S = __builtin_amdgcn_mfma_f32_32x32x16_bf16(Al, Qh[dc], S, 0, 0, 0);
      S = __builtin_amdgcn_mfma_f32_32x32x16_bf16(Ah, Ql[dc], S, 0, 0, 0);
    }
    __builtin_amdgcn_s_setprio(0);

    // --- online softmax in log2 units; tree + permlane cross-half reduce
    float m01 = fmaxf(S[0], S[1]),   m23 = fmaxf(S[2], S[3]);
    float m45 = fmaxf(S[4], S[5]),   m67 = fmaxf(S[6], S[7]);
    float m89 = fmaxf(S[8], S[9]),   mab = fmaxf(S[10], S[11]);
    float mcd = fmaxf(S[12], S[13]), mef = fmaxf(S[14], S[15]);
    float pmax = fmaxf(fmaxf(fmaxf(m01, m23), fmaxf(m45, m67)),
                       fmaxf(fmaxf(m89, mab), fmaxf(mcd, mef)));
    {
      auto sw = __builtin_amdgcn_permlane32_swap(uasf(pmax), uasf(pmax), false, false);
      pmax = fmaxf(fasu(sw[0]), fasu(sw[1]));
    }
    if (__any(pmax > mrun + 11.55f)) {      // defer-max (e^1 logit window)
      float mnew = fmaxf(mrun, pmax);
      float alpha = EXP2F(mrun - mnew);
      O0 *= alpha; O1 *= alpha; lrun *= alpha; mrun = mnew;
    }
    float p[16];
#pragma unroll
    for (int i = 0; i < 16; ++i) p[i] = EXP2F(S[i] - mrun);
    float s01 = p[0] + p[1],   s23 = p[2] + p[3];
    float s45 = p[4] + p[5],   s67 = p[6] + p[7];
    float s89 = p[8] + p[9],   sab = p[10] + p[11];
    float scd = p[12] + p[13], sef = p[14] + p[15];
    float ts = ((s01 + s23) + (s45 + s67)) + ((s89 + sab) + (scd + sef));
    {
      auto sw = __builtin_amdgcn_permlane32_swap(uasf(ts), uasf(ts), false, false);
      ts = fasu(sw[0]) + fasu(sw[1]);
    }
    lrun += ts;

    // --- O^T += V^T · P^T  (A = V^T frag from LDS, B = P^T in-register)
#define PV_CHUNK(kc_)                                                          \
    {                                                                          \
      const int b_ = 8 * (kc_);                                                \
      uint32_t X0, X1, Y0, Y1;                                                 \
      asm("v_cvt_pk_bf16_f32 %0, %1, %2" : "=v"(X0) : "v"(p[b_+0]), "v"(p[b_+1])); \
      asm("v_cvt_pk_bf16_f32 %0, %1, %2" : "=v"(X1) : "v"(p[b_+2]), "v"(p[b_+3])); \
      asm("v_cvt_pk_bf16_f32 %0, %1, %2" : "=v"(Y0) : "v"(p[b_+4]), "v"(p[b_+5])); \
      asm("v_cvt_pk_bf16_f32 %0, %1, %2" : "=v"(Y1) : "v"(p[b_+6]), "v"(p[b_+7])); \
      auto sw0 = __builtin_amdgcn_permlane32_swap(X0, Y0, false, false);       \
      auto sw1 = __builtin_amdgcn_permlane32_swap(X1, Y1, false, false);       \
      union { uint32_t u[4]; bf16x8 v; } cvb;                                  \
      cvb.u[0] = sw0[0]; cvb.u[1] = sw1[0];                                    \
      cvb.u[2] = sw0[1]; cvb.u[3] = sw1[1];                                    \
      bf16x8 Bp = cvb.v;                                                       \
      int vcol = 64 * cc + 32 * (kc_) + hioff;                                 \
      {                                                                        \
        bf16x8 Av = *(const bf16x8*)(cb + 32768 + lq * 256 + (vcol ^ swr));    \
        O0 = __builtin_amdgcn_mfma_f32_32x32x16_bf16(Av, Bp, O0, 0, 0, 0);     \
      }                                                                        \
      {                                                                        \
        bf16x8 Av = *(const bf16x8*)(cb + 32768 + (32 + lq) * 256 + (vcol ^ swr)); \
        O1 = __builtin_amdgcn_mfma_f32_32x32x16_bf16(Av, Bp, O1, 0, 0, 0);     \
      }                                                                        \
    }
    __builtin_amdgcn_s_setprio(1);
    PV_CHUNK(0)
    PV_CHUNK(1)
    __builtin_amdgcn_s_setprio(0);
#undef PV_CHUNK

    // tail: drain next tile's loads (flew during compute), then publish
    asm volatile("s_waitcnt vmcnt(0)" ::: "memory");
    __builtin_amdgcn_s_barrier();
    asm volatile("" ::: "memory");
    __builtin_amdgcn_sched_barrier(0);
  }

  // --- epilogue: 2-stage 4-way split-K merge, then direct f32x4 stores
  const int lsw = (l & 7) << 4;
#define DUMP(idx_)                                                             \
  {                                                                            \
    char* dd = smem + (idx_) * 8192 + l * 128;                                 \
    _Pragma("unroll")                                                          \
    for (int g = 0; g < 4; ++g) {                                              \
      f32x4 t0, t1;                                                            \
      _Pragma("unroll")                                                        \
      for (int j = 0; j < 4; ++j) { t0[j] = O0[4*g+j]; t1[j] = O1[4*g+j]; }    \
      *(f32x4*)(dd + ((g * 16) ^ lsw)) = t0;                                   \
      *(f32x4*)(dd + ((64 + g * 16) ^ lsw)) = t1;                              \
    }                                                                          \
    *(float*)(smem + MLB + (idx_) * 256 + lq * 8) = mrun;                      \
    *(float*)(smem + MLB + (idx_) * 256 + lq * 8 + 4) = lrun;                  \
  }
#define MERGE(idx_)                                                            \
  {                                                                            \
    const char* ds = smem + (idx_) * 8192 + l * 128;                           \
    float m1 = *(const float*)(smem + MLB + (idx_) * 256 + lq * 8);            \
    float l1 = *(const float*)(smem + MLB + (idx_) * 256 + lq * 8 + 4);        \
    float M = fmaxf(mrun, m1);                                                 \
    float a0 = EXP2F(mrun - M);                                                \
    float a1 = EXP2F(m1 - M);                                                  \
    lrun = lrun * a0 + l1 * a1;                                                \
    mrun = M;                                                                  \
    _Pragma("unroll")                                                          \
    for (int g = 0; g < 4; ++g) {                                              \
      f32x4 o1a = *(const f32x4*)(ds + ((g * 16) ^ lsw));                      \
      f32x4 o1b = *(const f32x4*)(ds + ((64 + g * 16) ^ lsw));                 \
      _Pragma("unroll")                                                        \
      for (int j = 0; j < 4; ++j) {                                            \
        O0[4*g+j] = O0[4*g+j] * a0 + o1a[j] * a1;                              \
        O1[4*g+j] = O1[4*g+j] * a0 + o1b[j] * a1;                              \
      }                                                                        \
    }                                                                          \
  }
  if (cc & 1) DUMP(r * 2 + (cc >> 1));      // cc=1 -> idx 2r, cc=3 -> idx 2r+1
  __syncthreads();
  if (!(cc & 1)) MERGE(r * 2 + (cc >> 1));  // cc=0 takes cc=1, cc=2 takes cc=3
  __syncthreads();
  if (cc == 2) DUMP(r * 2 + 1);
  __syncthreads();
  if (cc == 0) {
    MERGE(r * 2 + 1);
    float inv = 1.0f / lrun;
    float* orow = out + ((size_t)bb * NT + (size_t)qt * QT + r * 32 + lq) * 64;
#pragma unroll
    for (int g = 0; g < 4; ++g) {
      int d0 = 8 * g + (hi ? 4 : 0);
      f32x4 s0, s1;
#pragma unroll
      for (int j = 0; j < 4; ++j) { s0[j] = O0[4*g+j] * inv; s1[j] = O1[4*g+j] * inv; }
      *(f32x4*)(orow + d0) = s0;
      *(f32x4*)(orow + d0 + 32) = s1;
    }
  }
#undef DUMP
#undef MERGE
#undef STAGE_TILE
}

extern "C" void kernel_launch(void* const* d_in, const int* in_sizes, int n_in,
                              void* d_out, int out_size, void* d_ws, size_t ws_size,
                              hipStream_t stream) {
  const float* x  = (const float*)d_in[0];
  const float* Wk = (const float*)d_in[1];
  const float* bk = (const float*)d_in[2];
  const float* Wq = (const float*)d_in[3];
  const float* bq = (const float*)d_in[4];
  const float* Wv = (const float*)d_in[5];
  const float* bv = (const float*)d_in[6];
  float* out = (float*)d_out;

  const size_t NE = (size_t)NBATCH * NT * 64;
  unsigned short* ws = (unsigned short*)d_ws;
  unsigned short* khi = ws;
  unsigned short* klo = ws + NE;
  unsigned short* qhi = ws + 2 * NE;
  unsigned short* qlo = ws + 3 * NE;
  unsigned short* vt  = ws + 4 * NE;
  unsigned short* wt_hi = ws + 5 * NE;
  unsigned short* wt_lo = wt_hi + 192 * 64;

  prep_w<<<dim3(3), dim3(256), 0, stream>>>(Wk, Wq, Wv, wt_hi, wt_lo);
  proj_kernel<<<dim3((NBATCH * NT) / 64), dim3(256), 0, stream>>>(
      x, wt_hi, wt_lo, bk, bq, bv, khi, klo, qhi, qlo, vt);
  attn_kernel<<<dim3(NBATCH * (NT / QT)), dim3(1024), 0, stream>>>(
      khi, klo, qhi, qlo, vt, out);
}

// Round 17
// 65.408 us; speedup vs baseline: 1.3476x; 1.0295x over previous
//
#include <hip/hip_runtime.h>
#include <hip/hip_bf16.h>
#include <stdint.h>

#define NBATCH 16
#define NT 2048
#define NC 64
#define QT 128
#define KT 128
#define SC_LOG2E 11.5415603f  // 8 * log2(e)

typedef __bf16 bf16x8 __attribute__((ext_vector_type(8)));
typedef float f32x4 __attribute__((ext_vector_type(4)));
typedef float f32x16 __attribute__((ext_vector_type(16)));

#define Z16 {0.f,0.f,0.f,0.f,0.f,0.f,0.f,0.f,0.f,0.f,0.f,0.f,0.f,0.f,0.f,0.f}

extern "C" __device__ float __ocml_native_exp2_f32(float);
#define EXP2F(x) __ocml_native_exp2_f32(x)

static __device__ __forceinline__ unsigned short f2bf(float f) {
  __bf16 h = (__bf16)f;  // hardware RTNE convert
  union { __bf16 h; unsigned short u; } a; a.h = h; return a.u;
}
static __device__ __forceinline__ float bf2f(unsigned short h) {
  union { uint32_t u; float f; } a; a.u = ((uint32_t)h) << 16;
  return a.f;
}
static __device__ __forceinline__ float fasu(uint32_t u) {
  union { uint32_t u; float f; } a; a.u = u; return a.f;
}
static __device__ __forceinline__ uint32_t uasf(float f) {
  union { float f; uint32_t u; } a; a.f = f; return a.u;
}

#define GLD_LDS16(gsrc, ldst)                                                  \
  __builtin_amdgcn_global_load_lds(                                            \
      (const __attribute__((address_space(1))) void*)(gsrc),                   \
      (__attribute__((address_space(3))) void*)(ldst), 16, 0, 0)

// ---------------------------------------------------------------------------
// Kernel 0: one-time W transpose + hi/lo bf16 split. 3 blocks (k,q,v).
// ---------------------------------------------------------------------------
__global__ __launch_bounds__(256, 2) void prep_w(
    const float* __restrict__ Wk, const float* __restrict__ Wq,
    const float* __restrict__ Wv,
    unsigned short* __restrict__ wt_hi, unsigned short* __restrict__ wt_lo)
{
  __shared__ unsigned short hbuf[64][66];
  __shared__ unsigned short lbuf[64][66];
  const int m = (int)blockIdx.x;
  const float* Wm = (m == 0) ? Wk : (m == 1 ? Wq : Wv);
  const int tid = (int)threadIdx.x;
  for (int idx = tid; idx < 1024; idx += 256) {
    int c = idx >> 4, o4 = (idx & 15) * 4;
    float4 v = *(const float4*)(Wm + c * 64 + o4);
    float vals[4] = {v.x, v.y, v.z, v.w};
#pragma unroll
    for (int j = 0; j < 4; ++j) {
      unsigned short h = f2bf(vals[j]);
      hbuf[o4 + j][c] = h;
      lbuf[o4 + j][c] = f2bf(vals[j] - bf2f(h));
    }
  }
  __syncthreads();
  for (int idx = tid; idx < 1024; idx += 256) {
    int o = idx >> 4, c0 = (idx & 15) * 4;
    ushort4 hv, lv;
    hv.x = hbuf[o][c0]; hv.y = hbuf[o][c0 + 1];
    hv.z = hbuf[o][c0 + 2]; hv.w = hbuf[o][c0 + 3];
    lv.x = lbuf[o][c0]; lv.y = lbuf[o][c0 + 1];
    lv.z = lbuf[o][c0 + 2]; lv.w = lbuf[o][c0 + 3];
    *(ushort4*)(wt_hi + (size_t)(m * 64 + o) * 64 + c0) = hv;
    *(ushort4*)(wt_lo + (size_t)(m * 64 + o) * 64 + c0) = lv;
  }
}

// ---------------------------------------------------------------------------
// Kernel 1: q,k,v projections. 64 rows per block. (r16 validated)
// ---------------------------------------------------------------------------
__global__ __launch_bounds__(256, 2) void proj_kernel(
    const float* __restrict__ x,
    const unsigned short* __restrict__ wt_hi, const unsigned short* __restrict__ wt_lo,
    const float* __restrict__ bk, const float* __restrict__ bq, const float* __restrict__ bv,
    unsigned short* __restrict__ khi, unsigned short* __restrict__ klo,
    unsigned short* __restrict__ qhi, unsigned short* __restrict__ qlo,
    unsigned short* __restrict__ vt)
{
  __shared__ __align__(16) char smem[65536];
  const int XH = 0, XL = 8192, WTH = 16384, WTL = 40960, VTB = 0; // VTB aliases XH
  const int tid = (int)threadIdx.x;
  const int l = tid & 63, w = tid >> 6;
  const int lr = l & 15, lg = l >> 4;
  const int blk = (int)blockIdx.x;
  const int rowbase = blk * 64;
  const int bb = blk >> 5;          // 32 blocks per batch

  float4 xv[4];
#pragma unroll
  for (int j = 0; j < 4; ++j) {
    int c = tid + j * 256;
    int row = c >> 4, d0 = (c & 15) * 4;
    xv[j] = *(const float4*)(x + (size_t)(rowbase + row) * NC + d0);
  }
#pragma unroll
  for (int ch4 = 0; ch4 < 6; ++ch4) {
    int ch = ch4 * 4 + w;
    int d = ch * 1024 + l * 16;
    int swk = d ^ (((d >> 7) & 7) << 4);
    GLD_LDS16((const char*)wt_hi + swk, smem + WTH + ch * 1024);
    GLD_LDS16((const char*)wt_lo + swk, smem + WTL + ch * 1024);
  }
#pragma unroll
  for (int j = 0; j < 4; ++j) {
    int c = tid + j * 256;
    int row = c >> 4, d0 = (c & 15) * 4;
    unsigned short h0 = f2bf(xv[j].x), h1 = f2bf(xv[j].y), h2 = f2bf(xv[j].z), h3 = f2bf(xv[j].w);
    unsigned short m0 = f2bf(xv[j].x - bf2f(h0)), m1 = f2bf(xv[j].y - bf2f(h1));
    unsigned short m2 = f2bf(xv[j].z - bf2f(h2)), m3 = f2bf(xv[j].w - bf2f(h3));
    uint2 ph, pl;
    ph.x = (uint32_t)h0 | ((uint32_t)h1 << 16); ph.y = (uint32_t)h2 | ((uint32_t)h3 << 16);
    pl.x = (uint32_t)m0 | ((uint32_t)m1 << 16); pl.y = (uint32_t)m2 | ((uint32_t)m3 << 16);
    int byteoff = (row * 128 + d0 * 2) ^ ((row & 7) << 4);
    *(uint2*)(smem + XH + byteoff) = ph;
    *(uint2*)(smem + XL + byteoff) = pl;
  }
  __syncthreads();

  bf16x8 xh[2], xl[2];
  {
    int row = w * 16 + lr;
#pragma unroll
    for (int dc = 0; dc < 2; ++dc) {
      int byteoff = (row * 128 + (dc * 32 + lg * 8) * 2) ^ ((row & 7) << 4);
      xh[dc] = *(const bf16x8*)(smem + XH + byteoff);
      xl[dc] = *(const bf16x8*)(smem + XL + byteoff);
    }
  }
  f32x4 acc[12];
#pragma unroll
  for (int nb = 0; nb < 12; ++nb) {
    f32x4 a = {0.f, 0.f, 0.f, 0.f};
    int og = nb * 16 + lr;
#pragma unroll
    for (int dc = 0; dc < 2; ++dc) {
      int byteoff = (og * 128 + (dc * 32 + lg * 8) * 2) ^ ((og & 7) << 4);
      bf16x8 bh = *(const bf16x8*)(smem + WTH + byteoff);
      bf16x8 bl = *(const bf16x8*)(smem + WTL + byteoff);
      a = __builtin_amdgcn_mfma_f32_16x16x32_bf16(bh, xh[dc], a, 0, 0, 0);
      a = __builtin_amdgcn_mfma_f32_16x16x32_bf16(bl, xh[dc], a, 0, 0, 0);
      a = __builtin_amdgcn_mfma_f32_16x16x32_bf16(bh, xl[dc], a, 0, 0, 0);
    }
    acc[nb] = a;
  }
  __syncthreads();  // done reading XH/XL; VTB may now alias

  const int tloc = w * 16 + lr;
  const size_t gt = (size_t)(rowbase + tloc);
#pragma unroll
  for (int nb = 0; nb < 12; ++nb) {
    int ogb = (nb & 3) * 16 + lg * 4;
    const float* bp = (nb < 4) ? bk : (nb < 8 ? bq : bv);
    float4 bias = *(const float4*)(bp + ogb);
    float v0 = acc[nb][0] + bias.x, v1 = acc[nb][1] + bias.y,
          v2 = acc[nb][2] + bias.z, v3 = acc[nb][3] + bias.w;
    if (nb < 8) {
      if (nb >= 4) { v0 *= SC_LOG2E; v1 *= SC_LOG2E; v2 *= SC_LOG2E; v3 *= SC_LOG2E; }
      ushort4 hv, lv;
      hv.x = f2bf(v0); lv.x = f2bf(v0 - bf2f(hv.x));
      hv.y = f2bf(v1); lv.y = f2bf(v1 - bf2f(hv.y));
      hv.z = f2bf(v2); lv.z = f2bf(v2 - bf2f(hv.z));
      hv.w = f2bf(v3); lv.w = f2bf(v3 - bf2f(hv.w));
      unsigned short* dH = (nb < 4) ? khi : qhi;
      unsigned short* dL = (nb < 4) ? klo : qlo;
      *(ushort4*)(dH + gt * 64 + ogb) = hv;
      *(ushort4*)(dL + gt * 64 + ogb) = lv;
    } else {
      float vs[4] = {v0, v1, v2, v3};
#pragma unroll
      for (int r = 0; r < 4; ++r) {
        int o = ogb + r;
        int byteoff = (o * 128 + tloc * 2) ^ ((o & 7) << 4);
        *(unsigned short*)(smem + VTB + byteoff) = f2bf(vs[r]);
      }
    }
  }
  __syncthreads();
  for (int cc = tid; cc < 512; cc += 256) {
    int o = cc >> 3, t0 = (cc & 7) * 8;
    int byteoff = (o * 128 + t0 * 2) ^ ((o & 7) << 4);
    uint4 v = *(const uint4*)(smem + VTB + byteoff);
    *(uint4*)(vt + ((size_t)bb * 64 + o) * NT + (size_t)(blk & 31) * 64 + t0) = v;
  }
}

// ---------------------------------------------------------------------------
// Kernel 2: flash attention — deferred-softmax pipeline (r9 rotation logic,
// correctness-validated) on the 512-thread r15 shell (256-VGPR budget).
// 8 waves = 4 q-groups x 2 key-halves. Body(i): STAGE(i+1) || QK^T(i)->S_cur
// (unread) || softmax(S_prev)+PV(i-1). K double-buffered, V triple-buffered.
// Native exp2 (r16). 112 KB LDS, 1 block/CU.
// ---------------------------------------------------------------------------
__global__ __launch_bounds__(512, 2) void attn_kernel(
    const unsigned short* __restrict__ khi, const unsigned short* __restrict__ klo,
    const unsigned short* __restrict__ qhi, const unsigned short* __restrict__ qlo,
    const unsigned short* __restrict__ vt,
    float* __restrict__ out)
{
  __shared__ __align__(16) char smem[114688];
  const int KB_A = 0, KB_B = 32768;              // each: hi +0, lo +16384
  const int VB_0 = 65536, VB_1 = 81920, VB_2 = 98304;
  const int MLB = 40960;                         // epilogue m/l (aliases KB_B)
  const int tid = (int)threadIdx.x;
  const int l = tid & 63, w = tid >> 6;          // w in 0..7
  const int lq = l & 31;
  const bool hi = (l >= 32);
  const int hioff = hi ? 16 : 0;
  const int r = w & 3;                           // q-group: rows 32r..32r+31
  const int cc = w >> 2;                         // key half: keys 64cc..64cc+63
  const int lb = ((int)(blockIdx.x & 7) << 5) | ((int)blockIdx.x >> 3);
  const int bb = lb >> 4;
  const int qt = lb & 15;

  const char* kh_base = (const char*)(khi + (size_t)bb * NT * 64);
  const char* kl_base = (const char*)(klo + (size_t)bb * NT * 64);
  const char* v_base  = (const char*)(vt + (size_t)bb * 64 * NT);

#define STAGE_TILE(kb_, vb_, it_)                                              \
  do {                                                                         \
    const char* kh_t = kh_base + (size_t)(it_) * 16384;                        \
    const char* kl_t = kl_base + (size_t)(it_) * 16384;                        \
    const char* v_tb = v_base + (size_t)(it_) * 256;                           \
    _Pragma("unroll")                                                          \
    for (int j = 0; j < 2; ++j) {                                              \
      int ch = 2 * w + j;                                                      \
      int d = ch * 1024 + l * 16;                                              \
      int swk = d ^ (((d >> 7) & 7) << 4);                                     \
      GLD_LDS16(kh_t + swk, smem + (kb_) + ch * 1024);                         \
      GLD_LDS16(kl_t + swk, smem + (kb_) + 16384 + ch * 1024);                 \
      int o = d >> 8;                                                          \
      int swv = (d ^ ((o & 7) << 4)) & 255;                                    \
      GLD_LDS16(v_tb + (size_t)o * 4096 + swv, smem + (vb_) + ch * 1024);      \
    }                                                                          \
  } while (0)

  // prologue: stage tiles 0,1; Q fragments to regs
  STAGE_TILE(KB_A, VB_0, 0);
  STAGE_TILE(KB_B, VB_1, 1);
  bf16x8 Qh[4], Ql[4];
  {
    const char* qh_t = (const char*)qhi + ((size_t)bb * NT + (size_t)qt * QT) * 128;
    const char* ql_t = (const char*)qlo + ((size_t)bb * NT + (size_t)qt * QT) * 128;
    int qrow = r * 32 + lq;
#pragma unroll
    for (int dc = 0; dc < 4; ++dc) {
      Qh[dc] = *(const bf16x8*)(qh_t + qrow * 128 + dc * 32 + hioff);
      Ql[dc] = *(const bf16x8*)(ql_t + qrow * 128 + dc * 32 + hioff);
    }
  }
  asm volatile("s_waitcnt vmcnt(0)" ::: "memory");
  __builtin_amdgcn_s_barrier();
  asm volatile("" ::: "memory");

  f32x16 O0 = Z16, O1 = Z16;
  float mrun = -1e30f, lrun = 0.f;
  const int swr = (lq & 7) << 4;

  // QK^T of one tile from K buffer kb_ into SC0_/SC1_ (two chains, 3-term)
#define QK_TILE(kb_, SC0_, SC1_)                                               \
  {                                                                            \
    int row0_ = cc * 64 + lq;                                                  \
    int row1_ = row0_ + 32;                                                    \
    __builtin_amdgcn_s_setprio(1);                                             \
    _Pragma("unroll")                                                          \
    for (int dc = 0; dc < 4; ++dc) {                                           \
      int cchunk_ = (dc * 32 + hioff) ^ swr;                                   \
      bf16x8 Ah0_ = *(const bf16x8*)(smem + (kb_) + row0_ * 128 + cchunk_);    \
      bf16x8 Al0_ = *(const bf16x8*)(smem + (kb_) + 16384 + row0_ * 128 + cchunk_); \
      bf16x8 Ah1_ = *(const bf16x8*)(smem + (kb_) + row1_ * 128 + cchunk_);    \
      bf16x8 Al1_ = *(const bf16x8*)(smem + (kb_) + 16384 + row1_ * 128 + cchunk_); \
      SC0_ = __builtin_amdgcn_mfma_f32_32x32x16_bf16(Ah0_, Qh[dc], SC0_, 0, 0, 0); \
      SC1_ = __builtin_amdgcn_mfma_f32_32x32x16_bf16(Ah1_, Qh[dc], SC1_, 0, 0, 0); \
      SC0_ = __builtin_amdgcn_mfma_f32_32x32x16_bf16(Al0_, Qh[dc], SC0_, 0, 0, 0); \
      SC1_ = __builtin_amdgcn_mfma_f32_32x32x16_bf16(Al1_, Qh[dc], SC1_, 0, 0, 0); \
      SC0_ = __builtin_amdgcn_mfma_f32_32x32x16_bf16(Ah0_, Ql[dc], SC0_, 0, 0, 0); \
      SC1_ = __builtin_amdgcn_mfma_f32_32x32x16_bf16(Ah1_, Ql[dc], SC1_, 0, 0, 0); \
    }                                                                          \
    __builtin_amdgcn_s_setprio(0);                                             \
  }

  // softmax of a COMPLETED S pair + PV from V buffer vb_
#define SMPV(SP0_, SP1_, vb_)                                                  \
  {                                                                            \
    float a01 = fmaxf(SP0_[0], SP0_[1]),   a23 = fmaxf(SP0_[2], SP0_[3]);      \
    float a45 = fmaxf(SP0_[4], SP0_[5]),   a67 = fmaxf(SP0_[6], SP0_[7]);      \
    float a89 = fmaxf(SP0_[8], SP0_[9]),   aab = fmaxf(SP0_[10], SP0_[11]);    \
    float acd = fmaxf(SP0_[12], SP0_[13]), aef = fmaxf(SP0_[14], SP0_[15]);    \
    float pmax = fmaxf(fmaxf(fmaxf(a01, a23), fmaxf(a45, a67)),                \
                       fmaxf(fmaxf(a89, aab), fmaxf(acd, aef)));               \
    a01 = fmaxf(SP1_[0], SP1_[1]);   a23 = fmaxf(SP1_[2], SP1_[3]);            \
    a45 = fmaxf(SP1_[4], SP1_[5]);   a67 = fmaxf(SP1_[6], SP1_[7]);            \
    a89 = fmaxf(SP1_[8], SP1_[9]);   aab = fmaxf(SP1_[10], SP1_[11]);          \
    acd = fmaxf(SP1_[12], SP1_[13]); aef = fmaxf(SP1_[14], SP1_[15]);          \
    pmax = fmaxf(pmax, fmaxf(fmaxf(fmaxf(a01, a23), fmaxf(a45, a67)),          \
                             fmaxf(fmaxf(a89, aab), fmaxf(acd, aef))));        \
    {                                                                          \
      auto sw_ = __builtin_amdgcn_permlane32_swap(uasf(pmax), uasf(pmax), false, false); \
      pmax = fmaxf(fasu(sw_[0]), fasu(sw_[1]));                                \
    }                                                                          \
    if (__any(pmax > mrun + 11.55f)) {                                         \
      float mnew = fmaxf(mrun, pmax);                                          \
      float alpha = EXP2F(mrun - mnew);                                        \
      O0 *= alpha; O1 *= alpha; lrun *= alpha; mrun = mnew;                    \
    }                                                                          \
    float p0[16], p1[16];                                                      \
    float ts = 0.f;                                                            \
    _Pragma("unroll")                                                          \
    for (int i = 0; i < 16; ++i) { p0[i] = EXP2F(SP0_[i] - mrun); ts += p0[i]; } \
    _Pragma("unroll")                                                          \
    for (int i = 0; i < 16; ++i) { p1[i] = EXP2F(SP1_[i] - mrun); ts += p1[i]; } \
    {                                                                          \
      auto sw_ = __builtin_amdgcn_permlane32_swap(uasf(ts), uasf(ts), false, false); \
      ts = fasu(sw_[0]) + fasu(sw_[1]);                                        \
    }                                                                          \
    lrun += ts;                                                                \
    __builtin_amdgcn_s_setprio(1);                                             \
    _Pragma("unroll")                                                          \
    for (int kc = 0; kc < 4; ++kc) {                                           \
      const int b_ = 8 * (kc & 1);                                             \
      uint32_t X0, X1, Y0, Y1;                                                 \
      if (kc < 2) {                                                            \
        asm("v_cvt_pk_bf16_f32 %0, %1, %2" : "=v"(X0) : "v"(p0[b_+0]), "v"(p0[b_+1])); \
        asm("v_cvt_pk_bf16_f32 %0, %1, %2" : "=v"(X1) : "v"(p0[b_+2]), "v"(p0[b_+3])); \
        asm("v_cvt_pk_bf16_f32 %0, %1, %2" : "=v"(Y0) : "v"(p0[b_+4]), "v"(p0[b_+5])); \
        asm("v_cvt_pk_bf16_f32 %0, %1, %2" : "=v"(Y1) : "v"(p0[b_+6]), "v"(p0[b_+7])); \
      } else {                                                                 \
        asm("v_cvt_pk_bf16_f32 %0, %1, %2" : "=v"(X0) : "v"(p1[b_+0]), "v"(p1[b_+1])); \
        asm("v_cvt_pk_bf16_f32 %0, %1, %2" : "=v"(X1) : "v"(p1[b_+2]), "v"(p1[b_+3])); \
        asm("v_cvt_pk_bf16_f32 %0, %1, %2" : "=v"(Y0) : "v"(p1[b_+4]), "v"(p1[b_+5])); \
        asm("v_cvt_pk_bf16_f32 %0, %1, %2" : "=v"(Y1) : "v"(p1[b_+6]), "v"(p1[b_+7])); \
      }                                                                        \
      auto sw0_ = __builtin_amdgcn_permlane32_swap(X0, Y0, false, false);      \
      auto sw1_ = __builtin_amdgcn_permlane32_swap(X1, Y1, false, false);      \
      union { uint32_t u[4]; bf16x8 v; } cvb_;                                 \
      cvb_.u[0] = sw0_[0]; cvb_.u[1] = sw1_[0];                                \
      cvb_.u[2] = sw0_[1]; cvb_.u[3] = sw1_[1];                                \
      int vcol_ = 128 * cc + 32 * kc + hioff;                                  \
      bf16x8 Av0_ = *(const bf16x8*)(smem + (vb_) + lq * 256 + (vcol_ ^ swr)); \
      bf16x8 Av1_ = *(const bf16x8*)(smem + (vb_) + (32 + lq) * 256 + (vcol_ ^ swr)); \
      O0 = __builtin_amdgcn_mfma_f32_32x32x16_bf16(Av0_, cvb_.v, O0, 0, 0, 0); \
      O1 = __builtin_amdgcn_mfma_f32_32x32x16_bf16(Av1_, cvb_.v, O1, 0, 0, 0); \
    }                                                                          \
    __builtin_amdgcn_s_setprio(0);                                             \
  }

  // QK(0) -> SA; barrier so body(1)'s stage of tile 2 can reuse KB_A safely
  f32x16 SA0 = Z16, SA1 = Z16, SB0 = Z16, SB1 = Z16;
  QK_TILE(KB_A, SA0, SA1);
  asm volatile("s_waitcnt lgkmcnt(0)" ::: "memory");
  __builtin_amdgcn_s_barrier();
  asm volatile("" ::: "memory");

  int kbC = KB_B, kbN = KB_A;
  int vbP = VB_0, vbC = VB_1, vbN = VB_2;

#define BODY(i_, SP0_, SP1_, SC0_, SC1_, STG_)                                 \
  {                                                                            \
    if (STG_) STAGE_TILE(kbN, vbN, (i_) + 1);                                  \
    SC0_ = Z16; SC1_ = Z16;                                                    \
    QK_TILE(kbC, SC0_, SC1_);                                                  \
    SMPV(SP0_, SP1_, vbP);                                                     \
    asm volatile("s_waitcnt vmcnt(0)" ::: "memory");                           \
    __builtin_amdgcn_s_barrier();                                              \
    asm volatile("" ::: "memory");                                             \
    __builtin_amdgcn_sched_barrier(0);                                         \
  }
#define ROT()                                                                  \
  { int t_ = vbP; vbP = vbC; vbC = vbN; vbN = t_;                              \
    t_ = kbC; kbC = kbN; kbN = t_; }

#pragma unroll 1
  for (int ib = 0; ib < 7; ++ib) {
    BODY(2 * ib + 1, SA0, SA1, SB0, SB1, 1)
    ROT()
    BODY(2 * ib + 2, SB0, SB1, SA0, SA1, 1)
    ROT()
  }
  BODY(15, SA0, SA1, SB0, SB1, 0)
  // tail: softmax + PV for tile 15 (V(15) lives in vbC)
  SMPV(SB0, SB1, vbC);

  // --- epilogue: merge key halves (cc=1 -> cc=0), direct f32x4 stores
  const int lsw = (l & 7) << 4;
  if (cc == 1) {
    char* dd = smem + r * 8192 + l * 128;
#pragma unroll
    for (int g = 0; g < 4; ++g) {
      f32x4 t0, t1;
#pragma unroll
      for (int j = 0; j < 4; ++j) { t0[j] = O0[4*g+j]; t1[j] = O1[4*g+j]; }
      *(f32x4*)(dd + ((g * 16) ^ lsw)) = t0;
      *(f32x4*)(dd + ((64 + g * 16) ^ lsw)) = t1;
    }
    *(float*)(smem + MLB + r * 256 + lq * 8) = mrun;
    *(float*)(smem + MLB + r * 256 + lq * 8 + 4) = lrun;
  }
  __syncthreads();
  if (cc == 0) {
    const char* ds = smem + r * 8192 + l * 128;
    float m1 = *(const float*)(smem + MLB + r * 256 + lq * 8);
    float l1 = *(const float*)(smem + MLB + r * 256 + lq * 8 + 4);
    float M = fmaxf(mrun, m1);
    float a0 = EXP2F(mrun - M);
    float a1 = EXP2F(m1 - M);
    float Lt = lrun * a0 + l1 * a1;
    float inv = 1.0f / Lt;
    float f0 = a0 * inv, f1 = a1 * inv;
    float* orow = out + ((size_t)bb * NT + (size_t)qt * QT + r * 32 + lq) * 64;
#pragma unroll
    for (int g = 0; g < 4; ++g) {
      f32x4 o1a = *(const f32x4*)(ds + ((g * 16) ^ lsw));
      f32x4 o1b = *(const f32x4*)(ds + ((64 + g * 16) ^ lsw));
      int d0 = 8 * g + (hi ? 4 : 0);
      f32x4 s0, s1;
#pragma unroll
      for (int j = 0; j < 4; ++j) {
        s0[j] = O0[4*g+j] * f0 + o1a[j] * f1;
        s1[j] = O1[4*g+j] * f0 + o1b[j] * f1;
      }
      *(f32x4*)(orow + d0) = s0;
      *(f32x4*)(orow + d0 + 32) = s1;
    }
  }
#undef BODY
#undef ROT
#undef SMPV
#undef QK_TILE
#undef STAGE_TILE
}

extern "C" void kernel_launch(void* const* d_in, const int* in_sizes, int n_in,
                              void* d_out, int out_size, void* d_ws, size_t ws_size,
                              hipStream_t stream) {
  const float* x  = (const float*)d_in[0];
  const float* Wk = (const float*)d_in[1];
  const float* bk = (const float*)d_in[2];
  const float* Wq = (const float*)d_in[3];
  const float* bq = (const float*)d_in[4];
  const float* Wv = (const float*)d_in[5];
  const float* bv = (const float*)d_in[6];
  float* out = (float*)d_out;

  const size_t NE = (size_t)NBATCH * NT * 64;
  unsigned short* ws = (unsigned short*)d_ws;
  unsigned short* khi = ws;
  unsigned short* klo = ws + NE;
  unsigned short* qhi = ws + 2 * NE;
  unsigned short* qlo = ws + 3 * NE;
  unsigned short* vt  = ws + 4 * NE;
  unsigned short* wt_hi = ws + 5 * NE;
  unsigned short* wt_lo = wt_hi + 192 * 64;

  prep_w<<<dim3(3), dim3(256), 0, stream>>>(Wk, Wq, Wv, wt_hi, wt_lo);
  proj_kernel<<<dim3((NBATCH * NT) / 64), dim3(256), 0, stream>>>(
      x, wt_hi, wt_lo, bk, bq, bv, khi, klo, qhi, qlo, vt);
  attn_kernel<<<dim3(NBATCH * (NT / QT)), dim3(512), 0, stream>>>(
      khi, klo, qhi, qlo, vt, out);
}